// Round 4
// baseline (337.590 us; speedup 1.0000x reference)
//
#include <hip/hip_runtime.h>
#include <hip/hip_bf16.h>

#define PAD 68            // fp32 LDS pitch (small kernels)
#define KP  72            // bf16 LDS pitch: 144 B row -> balanced bank use on b128 reads
#define SCALE 0.35355339059327379f

typedef __attribute__((ext_vector_type(8))) short bf16x8;
typedef __attribute__((ext_vector_type(4))) float f32x4;
#define MFMA_BF16 __builtin_amdgcn_mfma_f32_16x16x32_bf16

__device__ __forceinline__ short f2b(float f) {          // fp32 -> bf16 RNE
    unsigned u = __float_as_uint(f);
    u += 0x7fff + ((u >> 16) & 1);
    return (short)(u >> 16);
}
__device__ __forceinline__ float b2f(short h) {
    return __uint_as_float(((unsigned)(unsigned short)h) << 16);
}

__device__ __forceinline__ void fma16(float acc[16], float a, const float* b) {
    const float4* b4 = reinterpret_cast<const float4*>(b);
    float4 x0 = b4[0], x1 = b4[1], x2 = b4[2], x3 = b4[3];
    acc[0]  += a * x0.x; acc[1]  += a * x0.y; acc[2]  += a * x0.z; acc[3]  += a * x0.w;
    acc[4]  += a * x1.x; acc[5]  += a * x1.y; acc[6]  += a * x1.z; acc[7]  += a * x1.w;
    acc[8]  += a * x2.x; acc[9]  += a * x2.y; acc[10] += a * x2.z; acc[11] += a * x2.w;
    acc[12] += a * x3.x; acc[13] += a * x3.y; acc[14] += a * x3.z; acc[15] += a * x3.w;
}

// 4x4-register-tile 64x64x64 matmul step: acc = A(i0..i0+3, :) x B(:, j0..j0+3)
__device__ __forceinline__ void mm_tile(float acc[4][4],
                                        const float* __restrict__ A, int lda,
                                        const float* __restrict__ B,
                                        int i0, int j0) {
#pragma unroll
    for (int r = 0; r < 4; r++)
#pragma unroll
        for (int c = 0; c < 4; c++) acc[r][c] = 0.f;
#pragma unroll 4
    for (int k0 = 0; k0 < 64; k0 += 4) {
        float4 b0 = *reinterpret_cast<const float4*>(&B[(k0 + 0) * PAD + j0]);
        float4 b1 = *reinterpret_cast<const float4*>(&B[(k0 + 1) * PAD + j0]);
        float4 b2 = *reinterpret_cast<const float4*>(&B[(k0 + 2) * PAD + j0]);
        float4 b3 = *reinterpret_cast<const float4*>(&B[(k0 + 3) * PAD + j0]);
        float4 a0 = *reinterpret_cast<const float4*>(&A[(i0 + 0) * lda + k0]);
        float4 a1 = *reinterpret_cast<const float4*>(&A[(i0 + 1) * lda + k0]);
        float4 a2 = *reinterpret_cast<const float4*>(&A[(i0 + 2) * lda + k0]);
        float4 a3 = *reinterpret_cast<const float4*>(&A[(i0 + 3) * lda + k0]);
#define ROW_UPD(r, av) \
        acc[r][0] += av.x * b0.x + av.y * b1.x + av.z * b2.x + av.w * b3.x; \
        acc[r][1] += av.x * b0.y + av.y * b1.y + av.z * b2.y + av.w * b3.y; \
        acc[r][2] += av.x * b0.z + av.y * b1.z + av.z * b2.z + av.w * b3.z; \
        acc[r][3] += av.x * b0.w + av.y * b1.w + av.z * b2.w + av.w * b3.w;
        ROW_UPD(0, a0) ROW_UPD(1, a1) ROW_UPD(2, a2) ROW_UPD(3, a3)
#undef ROW_UPD
    }
}

// ---------- A: landmark pooling (Q,K -> Qlm,Klm fp32 + bf16, pre-scaled by SCALE/64) ----------
__global__ __launch_bounds__(256) void pool_kernel(const float* __restrict__ Q,
                                                   const float* __restrict__ K,
                                                   float* __restrict__ Qlm,
                                                   float* __restrict__ Klm,
                                                   short* __restrict__ Qlm_b,
                                                   short* __restrict__ Klm_b) {
    __shared__ float4 red[256];
    const int blk = blockIdx.x;
    const int t = threadIdx.x;
    const int d4 = t & 15;
    const int rg = t >> 4;
    const float4* Q4 = reinterpret_cast<const float4*>(Q);
    const float4* K4 = reinterpret_cast<const float4*>(K);

    float4 sQ = {0.f, 0.f, 0.f, 0.f}, sK = {0.f, 0.f, 0.f, 0.f};
#pragma unroll
    for (int rr = 0; rr < 4; rr++) {
        int row = blk * 64 + rg * 4 + rr;
        int off4 = (row << 4) + d4;
        float4 q = Q4[off4], k = K4[off4];
        sQ.x += q.x; sQ.y += q.y; sQ.z += q.z; sQ.w += q.w;
        sK.x += k.x; sK.y += k.y; sK.z += k.z; sK.w += k.w;
    }
    const float c = SCALE * (1.0f / 64.0f);
    red[t] = sQ;
    __syncthreads();
    if (t < 16) {
        float4 s = {0.f, 0.f, 0.f, 0.f};
#pragma unroll
        for (int g = 0; g < 16; g++) {
            float4 v = red[g * 16 + t];
            s.x += v.x; s.y += v.y; s.z += v.z; s.w += v.w;
        }
        s.x *= c; s.y *= c; s.z *= c; s.w *= c;
        reinterpret_cast<float4*>(Qlm + blk * 64)[t] = s;
        ushort4 ub = { (unsigned short)f2b(s.x), (unsigned short)f2b(s.y),
                       (unsigned short)f2b(s.z), (unsigned short)f2b(s.w) };
        *reinterpret_cast<ushort4*>(&Qlm_b[blk * 64 + t * 4]) = ub;
    }
    __syncthreads();
    red[t] = sK;
    __syncthreads();
    if (t < 16) {
        float4 s = {0.f, 0.f, 0.f, 0.f};
#pragma unroll
        for (int g = 0; g < 16; g++) {
            float4 v = red[g * 16 + t];
            s.x += v.x; s.y += v.y; s.z += v.z; s.w += v.w;
        }
        s.x *= c; s.y *= c; s.z *= c; s.w *= c;
        reinterpret_cast<float4*>(Klm + blk * 64)[t] = s;
        ushort4 ub = { (unsigned short)f2b(s.x), (unsigned short)f2b(s.y),
                       (unsigned short)f2b(s.z), (unsigned short)f2b(s.w) };
        *reinterpret_cast<ushort4*>(&Klm_b[blk * 64 + t * 4]) = ub;
    }
}

// ---------- B: K2 = softmax(Qlm Klm^T), global col-sum max ----------
__global__ __launch_bounds__(256) void k2_kernel(const float* __restrict__ Qlm,
                                                 const float* __restrict__ Klm,
                                                 float* __restrict__ K2g,
                                                 unsigned* __restrict__ colmax) {
    __shared__ float Ql[64 * PAD], Kl[64 * PAD], S2[64 * PAD];
    const int bh = blockIdx.x, t = threadIdx.x;
#pragma unroll
    for (int n = 0; n < 16; n++) {
        int f = t + n * 256;
        Ql[(f >> 6) * PAD + (f & 63)] = Qlm[bh * 4096 + f];
        Kl[(f >> 6) * PAD + (f & 63)] = Klm[bh * 4096 + f];
    }
    __syncthreads();
    const int i = t >> 2, j0 = (t & 3) * 16;
    float acc[16];
#pragma unroll
    for (int u = 0; u < 16; u++) acc[u] = 0.f;
    const float4* Ql4 = reinterpret_cast<const float4*>(Ql);
    const float4* Kl4 = reinterpret_cast<const float4*>(Kl);
    for (int k4 = 0; k4 < 16; k4++) {
        float4 a = Ql4[i * 17 + k4];
#pragma unroll
        for (int u = 0; u < 16; u++) {
            float4 b = Kl4[(j0 + u) * 17 + k4];
            acc[u] += a.x * b.x + a.y * b.y + a.z * b.z + a.w * b.w;
        }
    }
#pragma unroll
    for (int u = 0; u < 16; u++) S2[i * PAD + j0 + u] = acc[u];
    __syncthreads();
    if (t < 64) {
        float m = -1e30f;
        for (int j = 0; j < 64; j++) m = fmaxf(m, S2[t * PAD + j]);
        float sum = 0.f;
        for (int j = 0; j < 64; j++) {
            float e = __expf(S2[t * PAD + j] - m);
            S2[t * PAD + j] = e; sum += e;
        }
        float inv = 1.0f / sum;
        for (int j = 0; j < 64; j++) S2[t * PAD + j] *= inv;
    }
    __syncthreads();
#pragma unroll
    for (int n = 0; n < 16; n++) {
        int f = t + n * 256;
        K2g[bh * 4096 + f] = S2[(f >> 6) * PAD + (f & 63)];
    }
    if (t < 64) {
        float c = 0.f;
        for (int ii = 0; ii < 64; ii++) c += S2[ii * PAD + t];
        atomicMax(colmax, __float_as_uint(c));
    }
}

// ---------- C+D fused: blocks 0..63 Newton-Schulz inverse; blocks 64..2111 k3v
//            (2048 blocks x 2 key-tiles each -> max cross-block latency hiding). ----------
__global__ __launch_bounds__(256) void fused_inv_k3v(const short* __restrict__ Qlm_b,
                                                     const float* __restrict__ K,
                                                     const float* __restrict__ V,
                                                     float* __restrict__ W2acc,
                                                     float* __restrict__ rowsum3,
                                                     const float* __restrict__ K2g,
                                                     const unsigned* __restrict__ colmax,
                                                     float* __restrict__ K2invg) {
    // union: inverse needs 3 x 64*PAD fp32 (52224 B); k3v needs 3 x 64*KP bf16 (27648 B)
    __shared__ __align__(16) char smem[64 * PAD * 4 * 3];
    const int t = threadIdx.x;

    if (blockIdx.x < 64) {
        // ================= Newton-Schulz inverse (6 iters, 4x4 reg tiles) ========
        float* Vb = reinterpret_cast<float*>(smem);
        float* Ab = Vb + 64 * PAD;
        float* Tb = Ab + 64 * PAD;
        const int bh = blockIdx.x;
        const float sc = 1.0f / __uint_as_float(*colmax);
        const float* Kg = K2g + bh * 4096;
#pragma unroll
        for (int n = 0; n < 16; n++) {
            int f = t + n * 256;
            Vb[(f >> 6) * PAD + (f & 63)] = sc * Kg[(f & 63) * 64 + (f >> 6)];
        }
        __syncthreads();
        const int i0 = (t >> 4) * 4, j0 = (t & 15) * 4;
        float acc[4][4], vacc[4][4];
        for (int iter = 0; iter < 6; iter++) {
            mm_tile(acc, Kg, 64, Vb, i0, j0);
#pragma unroll
            for (int r = 0; r < 4; r++)
                *reinterpret_cast<float4*>(&Ab[(i0 + r) * PAD + j0]) =
                    make_float4(acc[r][0], acc[r][1], acc[r][2], acc[r][3]);
            __syncthreads();
            mm_tile(acc, Vb, PAD, Ab, i0, j0);
#pragma unroll
            for (int r = 0; r < 4; r++) {
                float4 v = *reinterpret_cast<const float4*>(&Vb[(i0 + r) * PAD + j0]);
                vacc[r][0] = 13.f * v.x - 15.f * acc[r][0];
                vacc[r][1] = 13.f * v.y - 15.f * acc[r][1];
                vacc[r][2] = 13.f * v.z - 15.f * acc[r][2];
                vacc[r][3] = 13.f * v.w - 15.f * acc[r][3];
                *reinterpret_cast<float4*>(&Tb[(i0 + r) * PAD + j0]) =
                    make_float4(acc[r][0], acc[r][1], acc[r][2], acc[r][3]);
            }
            __syncthreads();
            mm_tile(acc, Tb, PAD, Ab, i0, j0);
#pragma unroll
            for (int r = 0; r < 4; r++) {
                vacc[r][0] += 7.f * acc[r][0];
                vacc[r][1] += 7.f * acc[r][1];
                vacc[r][2] += 7.f * acc[r][2];
                vacc[r][3] += 7.f * acc[r][3];
                *reinterpret_cast<float4*>(&Vb[(i0 + r) * PAD + j0]) =
                    make_float4(acc[r][0], acc[r][1], acc[r][2], acc[r][3]);
            }
            __syncthreads();
            mm_tile(acc, Vb, PAD, Ab, i0, j0);
#pragma unroll
            for (int r = 0; r < 4; r++) {
                vacc[r][0] -= acc[r][0]; vacc[r][1] -= acc[r][1];
                vacc[r][2] -= acc[r][2]; vacc[r][3] -= acc[r][3];
            }
            __syncthreads();
#pragma unroll
            for (int r = 0; r < 4; r++)
                *reinterpret_cast<float4*>(&Vb[(i0 + r) * PAD + j0]) =
                    make_float4(0.25f * vacc[r][0], 0.25f * vacc[r][1],
                                0.25f * vacc[r][2], 0.25f * vacc[r][3]);
            __syncthreads();
        }
#pragma unroll
        for (int n = 0; n < 16; n++) {
            int f = t + n * 256;
            K2invg[bh * 4096 + f] = Vb[(f >> 6) * PAD + (f & 63)];
        }
        return;
    }

    // ================= k3v: W2acc += exp(Qlm (SCALE*K)^T) @ V =================
    short* Kt = reinterpret_cast<short*>(smem);            // B (mm1): [key][dim]
    short* Vt = Kt + 64 * KP;                              // B (mm2): [dim][key]
    short* Eb = Vt + 64 * KP;                              // A (mm2): [landmark][key]
    const int idx = blockIdx.x - 64;
    const int chunk = idx & 31, bh = idx >> 5;             // 32 chunks x 64 bh
    const int w = t >> 6, lane = t & 63, quad = lane >> 4, l15 = lane & 15;
    const float4* K4 = reinterpret_cast<const float4*>(K);
    const float4* V4 = reinterpret_cast<const float4*>(V);
    const int dg = t & 15;          // dim-group 0..15 (float4 index)
    const int kr = t >> 4;          // K staging: key row base; V staging: key-group
    const int bhBase = bh * 4096;

    // A fragments straight from Qlm_b (bf16, L2-resident) — no Qs staging
    const bf16x8* Qb = reinterpret_cast<const bf16x8*>(Qlm_b + bh * 4096);
    bf16x8 a0 = Qb[(w * 16 + l15) * 8 + quad];
    bf16x8 a1 = Qb[(w * 16 + l15) * 8 + quad + 4];

    f32x4 oacc[4];
    float rsum[4];
#pragma unroll
    for (int nt = 0; nt < 4; nt++) { oacc[nt] = (f32x4){0.f, 0.f, 0.f, 0.f}; rsum[nt] = 0.f; }

    const int sb0 = chunk * 128;
    for (int tile = 0; tile < 2; tile++) {
        const int sb = sb0 + tile * 64;
        __syncthreads();   // prev tile's MFMA done reading Kt/Vt
        // ---- stage K (scaled, row-major): rows kr+16n at dim-group dg ----
#pragma unroll
        for (int n = 0; n < 4; n++) {
            float4 kk = K4[(bhBase + sb + kr + 16 * n) * 16 + dg];
            ushort4 uk = { (unsigned short)f2b(SCALE * kk.x), (unsigned short)f2b(SCALE * kk.y),
                           (unsigned short)f2b(SCALE * kk.z), (unsigned short)f2b(SCALE * kk.w) };
            *reinterpret_cast<ushort4*>(&Kt[(kr + 16 * n) * KP + dg * 4]) = uk;
        }
        // ---- stage V^T: thread owns keys kr*4..+3 at dims dg*4..+3 ----
        {
            float4 pv0 = V4[(bhBase + sb + kr * 4 + 0) * 16 + dg];
            float4 pv1 = V4[(bhBase + sb + kr * 4 + 1) * 16 + dg];
            float4 pv2 = V4[(bhBase + sb + kr * 4 + 2) * 16 + dg];
            float4 pv3 = V4[(bhBase + sb + kr * 4 + 3) * 16 + dg];
            ushort4 u0 = { (unsigned short)f2b(pv0.x), (unsigned short)f2b(pv1.x),
                           (unsigned short)f2b(pv2.x), (unsigned short)f2b(pv3.x) };
            ushort4 u1 = { (unsigned short)f2b(pv0.y), (unsigned short)f2b(pv1.y),
                           (unsigned short)f2b(pv2.y), (unsigned short)f2b(pv3.y) };
            ushort4 u2 = { (unsigned short)f2b(pv0.z), (unsigned short)f2b(pv1.z),
                           (unsigned short)f2b(pv2.z), (unsigned short)f2b(pv3.z) };
            ushort4 u3 = { (unsigned short)f2b(pv0.w), (unsigned short)f2b(pv1.w),
                           (unsigned short)f2b(pv2.w), (unsigned short)f2b(pv3.w) };
            *reinterpret_cast<ushort4*>(&Vt[(dg * 4 + 0) * KP + kr * 4]) = u0;
            *reinterpret_cast<ushort4*>(&Vt[(dg * 4 + 1) * KP + kr * 4]) = u1;
            *reinterpret_cast<ushort4*>(&Vt[(dg * 4 + 2) * KP + kr * 4]) = u2;
            *reinterpret_cast<ushort4*>(&Vt[(dg * 4 + 3) * KP + kr * 4]) = u3;
        }
        __syncthreads();
        // matmul1: S[m=16w.., n=key] = Qlm . Kt^T
#pragma unroll
        for (int nt = 0; nt < 4; nt++) {
            bf16x8 b0 = *reinterpret_cast<const bf16x8*>(&Kt[(nt * 16 + l15) * KP + quad * 8]);
            bf16x8 b1 = *reinterpret_cast<const bf16x8*>(&Kt[(nt * 16 + l15) * KP + quad * 8 + 32]);
            f32x4 c = {0.f, 0.f, 0.f, 0.f};
            c = MFMA_BF16(a0, b0, c, 0, 0, 0);
            c = MFMA_BF16(a1, b1, c, 0, 0, 0);
#pragma unroll
            for (int reg = 0; reg < 4; reg++) {
                float e = __expf(c[reg]);
                rsum[reg] += e;
                Eb[(w * 16 + quad * 4 + reg) * KP + nt * 16 + l15] = f2b(e);
            }
        }
        // matmul2: oacc += E . Vt^T   (wave reads only its own E rows -> no barrier)
        bf16x8 e0 = *reinterpret_cast<const bf16x8*>(&Eb[(w * 16 + l15) * KP + quad * 8]);
        bf16x8 e1 = *reinterpret_cast<const bf16x8*>(&Eb[(w * 16 + l15) * KP + quad * 8 + 32]);
#pragma unroll
        for (int nt = 0; nt < 4; nt++) {
            bf16x8 b0 = *reinterpret_cast<const bf16x8*>(&Vt[(nt * 16 + l15) * KP + quad * 8]);
            bf16x8 b1 = *reinterpret_cast<const bf16x8*>(&Vt[(nt * 16 + l15) * KP + quad * 8 + 32]);
            oacc[nt] = MFMA_BF16(e0, b0, oacc[nt], 0, 0, 0);
            oacc[nt] = MFMA_BF16(e1, b1, oacc[nt], 0, 0, 0);
        }
    }
    // reduce rowsums over the 16 lanes of each quad
#pragma unroll
    for (int reg = 0; reg < 4; reg++) {
        float s = rsum[reg];
        s += __shfl_xor(s, 1); s += __shfl_xor(s, 2);
        s += __shfl_xor(s, 4); s += __shfl_xor(s, 8);
        rsum[reg] = s;
    }
    const int row0 = w * 16 + quad * 4;
    if (l15 == 0) {
#pragma unroll
        for (int reg = 0; reg < 4; reg++)
            atomicAdd(&rowsum3[bh * 64 + row0 + reg], rsum[reg]);
    }
#pragma unroll
    for (int nt = 0; nt < 4; nt++)
#pragma unroll
        for (int reg = 0; reg < 4; reg++)
            atomicAdd(&W2acc[(bh * 64 + row0 + reg) * 64 + nt * 16 + l15], oacc[nt][reg]);
}

// ---------- E: W = inv(K2) @ (W2acc / rowsum3), emitted as bf16 hi/lo TRANSPOSED ----------
__global__ __launch_bounds__(256) void wmid_kernel(const float* __restrict__ K2invg,
                                                   const float* __restrict__ W2acc,
                                                   const float* __restrict__ rowsum3,
                                                   short* __restrict__ Wth,
                                                   short* __restrict__ Wtl) {
    __shared__ float I1[64 * PAD], W2[64 * PAD];
    const int bh = blockIdx.x, t = threadIdx.x;
#pragma unroll
    for (int n = 0; n < 16; n++) {
        int f = t + n * 256;
        int r = f >> 6;
        I1[r * PAD + (f & 63)] = K2invg[bh * 4096 + f];
        W2[r * PAD + (f & 63)] = W2acc[bh * 4096 + f] / rowsum3[bh * 64 + r];
    }
    __syncthreads();
    const int i = t >> 2, j0 = (t & 3) * 16;
    float acc[16];
#pragma unroll
    for (int u = 0; u < 16; u++) acc[u] = 0.f;
    for (int k = 0; k < 64; k++) fma16(acc, I1[i * PAD + k], W2 + k * PAD + j0);
    // transposed bf16 hi/lo store: Wth/Wtl[bh][dim][lm]
#pragma unroll
    for (int u = 0; u < 16; u++) {
        float wv = acc[u];
        short hi = f2b(wv);
        short lo = f2b(wv - b2f(hi));
        Wth[bh * 4096 + (j0 + u) * 64 + i] = hi;
        Wtl[bh * 4096 + (j0 + u) * 64 + i] = lo;
    }
}

// ---------- F (MFMA): X = softmax((SCALE*Q) Klm^T) @ W ----------
//            Barrier-free: A-frags from Q (global), B-frags from bf16 L2-resident
//            operands. LDS = Eb only (9 KB) -> high occupancy, pure streaming.
__global__ __launch_bounds__(256) void final_mfma(const float* __restrict__ Q,
                                                  const short* __restrict__ Klm_b,
                                                  const short* __restrict__ Wth,
                                                  const short* __restrict__ Wtl,
                                                  float* __restrict__ out) {
    __shared__ short Eb[64 * KP];   // A (mm2): [seqrow][landmark] — wave-private rows
    const int sc = blockIdx.x, bh = blockIdx.y, t = threadIdx.x;
    const int w = t >> 6, lane = t & 63, quad = lane >> 4, l15 = lane & 15;
    const int s0 = sc * 64;
    const int row = w * 16 + l15;

    // Q fragment loads (issued first, fly under everything below)
    const float* qrow = Q + ((size_t)bh * 4096 + s0 + row) * 64 + quad * 8;
    float4 qa = *reinterpret_cast<const float4*>(qrow);
    float4 qb = *reinterpret_cast<const float4*>(qrow + 4);
    float4 qc = *reinterpret_cast<const float4*>(qrow + 32);
    float4 qd = *reinterpret_cast<const float4*>(qrow + 36);

    // B-fragment base pointers (bf16, L2-resident: 8 KB per bh each)
    const bf16x8* Kb = reinterpret_cast<const bf16x8*>(Klm_b + bh * 4096);  // [lm][dim]
    const bf16x8* Hb = reinterpret_cast<const bf16x8*>(Wth + bh * 4096);    // [dim][lm]
    const bf16x8* Lb = reinterpret_cast<const bf16x8*>(Wtl + bh * 4096);    // [dim][lm]

    // build A fragments (scaled, bf16)
    bf16x8 a0, a1;
    a0[0] = f2b(SCALE * qa.x); a0[1] = f2b(SCALE * qa.y);
    a0[2] = f2b(SCALE * qa.z); a0[3] = f2b(SCALE * qa.w);
    a0[4] = f2b(SCALE * qb.x); a0[5] = f2b(SCALE * qb.y);
    a0[6] = f2b(SCALE * qb.z); a0[7] = f2b(SCALE * qb.w);
    a1[0] = f2b(SCALE * qc.x); a1[1] = f2b(SCALE * qc.y);
    a1[2] = f2b(SCALE * qc.z); a1[3] = f2b(SCALE * qc.w);
    a1[4] = f2b(SCALE * qd.x); a1[5] = f2b(SCALE * qd.y);
    a1[6] = f2b(SCALE * qd.z); a1[7] = f2b(SCALE * qd.w);

    // mm1: S = Q . Klm^T ; exp ; rowsum ; Eb
    float rsum[4] = {0.f, 0.f, 0.f, 0.f};
#pragma unroll
    for (int nt = 0; nt < 4; nt++) {
        bf16x8 b0 = Kb[(nt * 16 + l15) * 8 + quad];
        bf16x8 b1 = Kb[(nt * 16 + l15) * 8 + quad + 4];
        f32x4 c = {0.f, 0.f, 0.f, 0.f};
        c = MFMA_BF16(a0, b0, c, 0, 0, 0);
        c = MFMA_BF16(a1, b1, c, 0, 0, 0);
#pragma unroll
        for (int reg = 0; reg < 4; reg++) {
            float e = __expf(c[reg]);
            rsum[reg] += e;
            Eb[(w * 16 + quad * 4 + reg) * KP + nt * 16 + l15] = f2b(e);
        }
    }
#pragma unroll
    for (int reg = 0; reg < 4; reg++) {
        float s = rsum[reg];
        s += __shfl_xor(s, 1); s += __shfl_xor(s, 2);
        s += __shfl_xor(s, 4); s += __shfl_xor(s, 8);
        rsum[reg] = 1.0f / s;
    }
    // mm2: X = Eb . (Wh + Wl)   (wave reads only its own Eb rows -> no barrier)
    bf16x8 e0 = *reinterpret_cast<const bf16x8*>(&Eb[row * KP + quad * 8]);
    bf16x8 e1 = *reinterpret_cast<const bf16x8*>(&Eb[row * KP + quad * 8 + 32]);
    const int row0 = w * 16 + quad * 4;
#pragma unroll
    for (int nt = 0; nt < 4; nt++) {
        bf16x8 bh0 = Hb[(nt * 16 + l15) * 8 + quad];
        bf16x8 bh1 = Hb[(nt * 16 + l15) * 8 + quad + 4];
        bf16x8 bl0 = Lb[(nt * 16 + l15) * 8 + quad];
        bf16x8 bl1 = Lb[(nt * 16 + l15) * 8 + quad + 4];
        f32x4 c = {0.f, 0.f, 0.f, 0.f};
        c = MFMA_BF16(e0, bh0, c, 0, 0, 0);
        c = MFMA_BF16(e1, bh1, c, 0, 0, 0);
        c = MFMA_BF16(e0, bl0, c, 0, 0, 0);
        c = MFMA_BF16(e1, bl1, c, 0, 0, 0);
#pragma unroll
        for (int reg = 0; reg < 4; reg++)
            out[((size_t)bh * 4096 + s0 + row0 + reg) * 64 + nt * 16 + l15] = c[reg] * rsum[reg];
    }
}

extern "C" void kernel_launch(void* const* d_in, const int* in_sizes, int n_in,
                              void* d_out, int out_size, void* d_ws, size_t ws_size,
                              hipStream_t stream) {
    const float* Q = (const float*)d_in[0];
    const float* K = (const float*)d_in[1];
    const float* V = (const float*)d_in[2];
    float* out = (float*)d_out;
    float* ws = (float*)d_ws;

    float* Qlm     = ws;                                   // 262144 fp32
    float* Klm     = ws + 262144;                          // 262144 fp32
    float* K2      = ws + 524288;                          // 262144 fp32
    float* K2inv   = ws + 786432;                          // 262144 fp32
    short* Wth     = (short*)(ws + 1048576);               // 262144 bf16 (half of old Wg slot)
    short* Wtl     = (short*)(ws + 1179648);               // 262144 bf16
    float* W2acc   = ws + 1310720;                         // 262144 fp32, zeroed
    float* rowsum3 = ws + 1572864;                         // 4096 fp32, zeroed
    unsigned* colmax = (unsigned*)(ws + 1576960);          // 1, zeroed
    short* Qlm_b   = (short*)(ws + 1576964);               // 262144 bf16
    short* Klm_b   = (short*)(ws + 1708036);               // 262144 bf16

    hipMemsetAsync(W2acc, 0, (262144 + 4096 + 1) * sizeof(float), stream);

    pool_kernel<<<4096, 256, 0, stream>>>(Q, K, Qlm, Klm, Qlm_b, Klm_b);
    k2_kernel<<<64, 256, 0, stream>>>(Qlm, Klm, K2, colmax);
    // blocks 0..63: Newton-Schulz inverse; blocks 64..2111: k3v (32 chunks x 64 bh)
    fused_inv_k3v<<<2112, 256, 0, stream>>>(Qlm_b, K, V, W2acc, rowsum3, K2, colmax, K2inv);
    wmid_kernel<<<64, 256, 0, stream>>>(K2inv, W2acc, rowsum3, Wth, Wtl);
    final_mfma<<<dim3(64, 64), 256, 0, stream>>>(Q, Klm_b, Wth, Wtl, out);
}

// Round 5
// 313.697 us; speedup vs baseline: 1.0762x; 1.0762x over previous
//
#include <hip/hip_runtime.h>
#include <hip/hip_bf16.h>

#define PAD 68            // fp32 LDS pitch (small kernels)
#define KP  72            // bf16 LDS pitch: 144 B row -> balanced bank use on b128 reads
#define SCALE 0.35355339059327379f

typedef __attribute__((ext_vector_type(8))) short bf16x8;
typedef __attribute__((ext_vector_type(4))) float f32x4;
#define MFMA_BF16 __builtin_amdgcn_mfma_f32_16x16x32_bf16

__device__ __forceinline__ short f2b(float f) {          // fp32 -> bf16 RNE
    unsigned u = __float_as_uint(f);
    u += 0x7fff + ((u >> 16) & 1);
    return (short)(u >> 16);
}
__device__ __forceinline__ float b2f(short h) {
    return __uint_as_float(((unsigned)(unsigned short)h) << 16);
}

__device__ __forceinline__ void fma16(float acc[16], float a, const float* b) {
    const float4* b4 = reinterpret_cast<const float4*>(b);
    float4 x0 = b4[0], x1 = b4[1], x2 = b4[2], x3 = b4[3];
    acc[0]  += a * x0.x; acc[1]  += a * x0.y; acc[2]  += a * x0.z; acc[3]  += a * x0.w;
    acc[4]  += a * x1.x; acc[5]  += a * x1.y; acc[6]  += a * x1.z; acc[7]  += a * x1.w;
    acc[8]  += a * x2.x; acc[9]  += a * x2.y; acc[10] += a * x2.z; acc[11] += a * x2.w;
    acc[12] += a * x3.x; acc[13] += a * x3.y; acc[14] += a * x3.z; acc[15] += a * x3.w;
}

// swizzled short-index into a [64][64]-short (pitch 64) LDS tile:
// byte = row*128 + colS*2, XOR'd with (row&7)<<4 -> b128 reads 2-way conflict only
__device__ __forceinline__ int SWI(int row, int colS) {
    return (((row << 7) + (colS << 1)) ^ ((row & 7) << 4)) >> 1;
}

// ---------- A: landmark pooling (Q,K -> Qlm,Klm fp32 + bf16, pre-scaled by SCALE/64) ----------
__global__ __launch_bounds__(256) void pool_kernel(const float* __restrict__ Q,
                                                   const float* __restrict__ K,
                                                   float* __restrict__ Qlm,
                                                   float* __restrict__ Klm,
                                                   short* __restrict__ Qlm_b,
                                                   short* __restrict__ Klm_b) {
    __shared__ float4 red[256];
    const int blk = blockIdx.x;
    const int t = threadIdx.x;
    const int d4 = t & 15;
    const int rg = t >> 4;
    const float4* Q4 = reinterpret_cast<const float4*>(Q);
    const float4* K4 = reinterpret_cast<const float4*>(K);

    float4 sQ = {0.f, 0.f, 0.f, 0.f}, sK = {0.f, 0.f, 0.f, 0.f};
#pragma unroll
    for (int rr = 0; rr < 4; rr++) {
        int row = blk * 64 + rg * 4 + rr;
        int off4 = (row << 4) + d4;
        float4 q = Q4[off4], k = K4[off4];
        sQ.x += q.x; sQ.y += q.y; sQ.z += q.z; sQ.w += q.w;
        sK.x += k.x; sK.y += k.y; sK.z += k.z; sK.w += k.w;
    }
    const float c = SCALE * (1.0f / 64.0f);
    red[t] = sQ;
    __syncthreads();
    if (t < 16) {
        float4 s = {0.f, 0.f, 0.f, 0.f};
#pragma unroll
        for (int g = 0; g < 16; g++) {
            float4 v = red[g * 16 + t];
            s.x += v.x; s.y += v.y; s.z += v.z; s.w += v.w;
        }
        s.x *= c; s.y *= c; s.z *= c; s.w *= c;
        reinterpret_cast<float4*>(Qlm + blk * 64)[t] = s;
        ushort4 ub = { (unsigned short)f2b(s.x), (unsigned short)f2b(s.y),
                       (unsigned short)f2b(s.z), (unsigned short)f2b(s.w) };
        *reinterpret_cast<ushort4*>(&Qlm_b[blk * 64 + t * 4]) = ub;
    }
    __syncthreads();
    red[t] = sK;
    __syncthreads();
    if (t < 16) {
        float4 s = {0.f, 0.f, 0.f, 0.f};
#pragma unroll
        for (int g = 0; g < 16; g++) {
            float4 v = red[g * 16 + t];
            s.x += v.x; s.y += v.y; s.z += v.z; s.w += v.w;
        }
        s.x *= c; s.y *= c; s.z *= c; s.w *= c;
        reinterpret_cast<float4*>(Klm + blk * 64)[t] = s;
        ushort4 ub = { (unsigned short)f2b(s.x), (unsigned short)f2b(s.y),
                       (unsigned short)f2b(s.z), (unsigned short)f2b(s.w) };
        *reinterpret_cast<ushort4*>(&Klm_b[blk * 64 + t * 4]) = ub;
    }
}

// ---------- B: K2 = softmax(Qlm Klm^T), global col-sum max ----------
__global__ __launch_bounds__(256) void k2_kernel(const float* __restrict__ Qlm,
                                                 const float* __restrict__ Klm,
                                                 float* __restrict__ K2g,
                                                 unsigned* __restrict__ colmax) {
    __shared__ float Ql[64 * PAD], Kl[64 * PAD], S2[64 * PAD];
    const int bh = blockIdx.x, t = threadIdx.x;
#pragma unroll
    for (int n = 0; n < 16; n++) {
        int f = t + n * 256;
        Ql[(f >> 6) * PAD + (f & 63)] = Qlm[bh * 4096 + f];
        Kl[(f >> 6) * PAD + (f & 63)] = Klm[bh * 4096 + f];
    }
    __syncthreads();
    const int i = t >> 2, j0 = (t & 3) * 16;
    float acc[16];
#pragma unroll
    for (int u = 0; u < 16; u++) acc[u] = 0.f;
    const float4* Ql4 = reinterpret_cast<const float4*>(Ql);
    const float4* Kl4 = reinterpret_cast<const float4*>(Kl);
    for (int k4 = 0; k4 < 16; k4++) {
        float4 a = Ql4[i * 17 + k4];
#pragma unroll
        for (int u = 0; u < 16; u++) {
            float4 b = Kl4[(j0 + u) * 17 + k4];
            acc[u] += a.x * b.x + a.y * b.y + a.z * b.z + a.w * b.w;
        }
    }
#pragma unroll
    for (int u = 0; u < 16; u++) S2[i * PAD + j0 + u] = acc[u];
    __syncthreads();
    if (t < 64) {
        float m = -1e30f;
        for (int j = 0; j < 64; j++) m = fmaxf(m, S2[t * PAD + j]);
        float sum = 0.f;
        for (int j = 0; j < 64; j++) {
            float e = __expf(S2[t * PAD + j] - m);
            S2[t * PAD + j] = e; sum += e;
        }
        float inv = 1.0f / sum;
        for (int j = 0; j < 64; j++) S2[t * PAD + j] *= inv;
    }
    __syncthreads();
#pragma unroll
    for (int n = 0; n < 16; n++) {
        int f = t + n * 256;
        K2g[bh * 4096 + f] = S2[(f >> 6) * PAD + (f & 63)];
    }
    if (t < 64) {
        float c = 0.f;
        for (int ii = 0; ii < 64; ii++) c += S2[ii * PAD + t];
        atomicMax(colmax, __float_as_uint(c));
    }
}

// ---------- C+D fused: blocks 0..63 Newton-Schulz inverse (MFMA hi/lo bf16);
//            blocks 64..2111 k3v. ----------
__global__ __launch_bounds__(256) void fused_inv_k3v(const short* __restrict__ Qlm_b,
                                                     const float* __restrict__ K,
                                                     const float* __restrict__ V,
                                                     float* __restrict__ W2acc,
                                                     float* __restrict__ rowsum3,
                                                     const float* __restrict__ K2g,
                                                     const unsigned* __restrict__ colmax,
                                                     float* __restrict__ K2invg) {
    // inverse: 8 x [64][64]-short swizzled tiles = 64 KB; k3v: 3 x 64*KP = 27.6 KB
    __shared__ __align__(16) char smem[65536];
    const int t = threadIdx.x;
    const int w = t >> 6, lane = t & 63, quad = lane >> 4, l15 = lane & 15;

    if (blockIdx.x < 64) {
        // ===== Newton-Schulz inverse, MFMA bf16 hi/lo (4-term, ~2^-17 rel) ======
        short* Krh = reinterpret_cast<short*>(smem);       // K2 hi (row-major)
        short* Krl = Krh + 4096;                           // K2 lo
        short* Ath = Krl + 4096;                           // A^T hi
        short* Atl = Ath + 4096;
        short* B1h = Atl + 4096;                           // V^T / P / V'^T
        short* B1l = B1h + 4096;
        short* B2h = B1l + 4096;                           // V / Q2 / V'
        short* B2l = B2h + 4096;
        const int bh = blockIdx.x;
        const float scv = 1.0f / __uint_as_float(*colmax);
        const float* Kg = K2g + bh * 4096;

        // ---- stage Kr (hi/lo), B1 = scv*K2 (= V0^T), B2 = scv*K2^T (= V0) ----
#pragma unroll
        for (int n = 0; n < 4; n++) {
            int f4 = t + n * 256;
            int r = f4 >> 4, c0 = (f4 & 15) * 4;
            float4 kk = *reinterpret_cast<const float4*>(Kg + r * 64 + c0);
            short h0 = f2b(kk.x), h1 = f2b(kk.y), h2 = f2b(kk.z), h3 = f2b(kk.w);
            ushort4 uh = {(unsigned short)h0, (unsigned short)h1,
                          (unsigned short)h2, (unsigned short)h3};
            ushort4 ul = {(unsigned short)f2b(kk.x - b2f(h0)), (unsigned short)f2b(kk.y - b2f(h1)),
                          (unsigned short)f2b(kk.z - b2f(h2)), (unsigned short)f2b(kk.w - b2f(h3))};
            *reinterpret_cast<ushort4*>(&Krh[SWI(r, c0)]) = uh;
            *reinterpret_cast<ushort4*>(&Krl[SWI(r, c0)]) = ul;
            float s0 = scv * kk.x, s1 = scv * kk.y, s2 = scv * kk.z, s3 = scv * kk.w;
            short g0 = f2b(s0), g1 = f2b(s1), g2 = f2b(s2), g3 = f2b(s3);
            ushort4 vh = {(unsigned short)g0, (unsigned short)g1,
                          (unsigned short)g2, (unsigned short)g3};
            ushort4 vl = {(unsigned short)f2b(s0 - b2f(g0)), (unsigned short)f2b(s1 - b2f(g1)),
                          (unsigned short)f2b(s2 - b2f(g2)), (unsigned short)f2b(s3 - b2f(g3))};
            *reinterpret_cast<ushort4*>(&B1h[SWI(r, c0)]) = vh;
            *reinterpret_cast<ushort4*>(&B1l[SWI(r, c0)]) = vl;
            float t0 = scv * Kg[(c0 + 0) * 64 + r];
            float t1 = scv * Kg[(c0 + 1) * 64 + r];
            float t2 = scv * Kg[(c0 + 2) * 64 + r];
            float t3 = scv * Kg[(c0 + 3) * 64 + r];
            short e0 = f2b(t0), e1 = f2b(t1), e2 = f2b(t2), e3 = f2b(t3);
            ushort4 th = {(unsigned short)e0, (unsigned short)e1,
                          (unsigned short)e2, (unsigned short)e3};
            ushort4 tl = {(unsigned short)f2b(t0 - b2f(e0)), (unsigned short)f2b(t1 - b2f(e1)),
                          (unsigned short)f2b(t2 - b2f(e2)), (unsigned short)f2b(t3 - b2f(e3))};
            *reinterpret_cast<ushort4*>(&B2h[SWI(r, c0)]) = th;
            *reinterpret_cast<ushort4*>(&B2l[SWI(r, c0)]) = tl;
        }
        // V in fp32 registers: vreg[nt][reg] = V0[w*16+quad*4+reg][nt*16+l15]
        float vreg[4][4];
#pragma unroll
        for (int nt = 0; nt < 4; nt++) {
            float4 vv = *reinterpret_cast<const float4*>(
                Kg + (nt * 16 + l15) * 64 + w * 16 + quad * 4);
            vreg[nt][0] = scv * vv.x; vreg[nt][1] = scv * vv.y;
            vreg[nt][2] = scv * vv.z; vreg[nt][3] = scv * vv.w;
        }
        __syncthreads();

        // hi/lo 4-term product helper: c += L(row w16+l15) x B(col-tile nt), K=64
#define LOADA(Lh, Ll) \
        bf16x8 ah0 = *reinterpret_cast<const bf16x8*>(&Lh[SWI(w * 16 + l15, quad * 8)]); \
        bf16x8 ah1 = *reinterpret_cast<const bf16x8*>(&Lh[SWI(w * 16 + l15, quad * 8 + 32)]); \
        bf16x8 al0 = *reinterpret_cast<const bf16x8*>(&Ll[SWI(w * 16 + l15, quad * 8)]); \
        bf16x8 al1 = *reinterpret_cast<const bf16x8*>(&Ll[SWI(w * 16 + l15, quad * 8 + 32)]);
#define PRODNT(Bh, Bl, nt, c) { \
        bf16x8 bh0 = *reinterpret_cast<const bf16x8*>(&Bh[SWI(nt * 16 + l15, quad * 8)]); \
        bf16x8 bh1 = *reinterpret_cast<const bf16x8*>(&Bh[SWI(nt * 16 + l15, quad * 8 + 32)]); \
        bf16x8 bl0 = *reinterpret_cast<const bf16x8*>(&Bl[SWI(nt * 16 + l15, quad * 8)]); \
        bf16x8 bl1 = *reinterpret_cast<const bf16x8*>(&Bl[SWI(nt * 16 + l15, quad * 8 + 32)]); \
        c = MFMA_BF16(ah0, bh0, c, 0, 0, 0); c = MFMA_BF16(ah1, bh1, c, 0, 0, 0); \
        c = MFMA_BF16(ah0, bl0, c, 0, 0, 0); c = MFMA_BF16(ah1, bl1, c, 0, 0, 0); \
        c = MFMA_BF16(al0, bh0, c, 0, 0, 0); c = MFMA_BF16(al1, bh1, c, 0, 0, 0); \
        c = MFMA_BF16(al0, bl0, c, 0, 0, 0); c = MFMA_BF16(al1, bl1, c, 0, 0, 0); }

        for (int iter = 0; iter < 6; iter++) {
            // M1: A = K·V  (B = B1 = V^T) -> write A^T hi/lo
            {
                LOADA(Krh, Krl)
#pragma unroll
                for (int nt = 0; nt < 4; nt++) {
                    f32x4 c = {0.f, 0.f, 0.f, 0.f};
                    PRODNT(B1h, B1l, nt, c)
                    short h0 = f2b(c[0]), h1 = f2b(c[1]), h2 = f2b(c[2]), h3 = f2b(c[3]);
                    ushort4 uh = {(unsigned short)h0, (unsigned short)h1,
                                  (unsigned short)h2, (unsigned short)h3};
                    ushort4 ul = {(unsigned short)f2b(c[0] - b2f(h0)),
                                  (unsigned short)f2b(c[1] - b2f(h1)),
                                  (unsigned short)f2b(c[2] - b2f(h2)),
                                  (unsigned short)f2b(c[3] - b2f(h3))};
                    *reinterpret_cast<ushort4*>(&Ath[SWI(nt * 16 + l15, w * 16 + quad * 4)]) = uh;
                    *reinterpret_cast<ushort4*>(&Atl[SWI(nt * 16 + l15, w * 16 + quad * 4)]) = ul;
                }
            }
            __syncthreads();
            // M2: P = V·A (LHS = B2 own rows, B = A^T) -> p regs + P rows into B1
            float p[4][4];
            {
                LOADA(B2h, B2l)
#pragma unroll
                for (int nt = 0; nt < 4; nt++) {
                    f32x4 c = {0.f, 0.f, 0.f, 0.f};
                    PRODNT(Ath, Atl, nt, c)
#pragma unroll
                    for (int reg = 0; reg < 4; reg++) {
                        p[nt][reg] = c[reg];
                        short hh = f2b(c[reg]);
                        B1h[SWI(w * 16 + quad * 4 + reg, nt * 16 + l15)] = hh;
                        B1l[SWI(w * 16 + quad * 4 + reg, nt * 16 + l15)] = f2b(c[reg] - b2f(hh));
                    }
                }
            }
            __syncthreads();
            // M3: Q2 = P·A (LHS = B1 own rows) -> q regs + Q2 rows into B2
            float q[4][4];
            {
                LOADA(B1h, B1l)
#pragma unroll
                for (int nt = 0; nt < 4; nt++) {
                    f32x4 c = {0.f, 0.f, 0.f, 0.f};
                    PRODNT(Ath, Atl, nt, c)
#pragma unroll
                    for (int reg = 0; reg < 4; reg++) {
                        q[nt][reg] = c[reg];
                        short hh = f2b(c[reg]);
                        B2h[SWI(w * 16 + quad * 4 + reg, nt * 16 + l15)] = hh;
                        B2l[SWI(w * 16 + quad * 4 + reg, nt * 16 + l15)] = f2b(c[reg] - b2f(hh));
                    }
                }
            }
            __syncthreads();
            // M4: R = Q2·A (LHS = B2 own rows); combo in fp32 regs; publish V'
            {
                LOADA(B2h, B2l)
#pragma unroll
                for (int nt = 0; nt < 4; nt++) {
                    f32x4 c = {0.f, 0.f, 0.f, 0.f};
                    PRODNT(Ath, Atl, nt, c)
#pragma unroll
                    for (int reg = 0; reg < 4; reg++)
                        vreg[nt][reg] = 0.25f * (13.f * vreg[nt][reg] - 15.f * p[nt][reg]
                                                 + 7.f * q[nt][reg] - c[reg]);
                }
            }
            // write V' rows into B2 (own rows) and V'^T into B1 (hi/lo)
#pragma unroll
            for (int nt = 0; nt < 4; nt++) {
                short h0 = f2b(vreg[nt][0]), h1 = f2b(vreg[nt][1]);
                short h2 = f2b(vreg[nt][2]), h3 = f2b(vreg[nt][3]);
                short g0 = f2b(vreg[nt][0] - b2f(h0)), g1 = f2b(vreg[nt][1] - b2f(h1));
                short g2 = f2b(vreg[nt][2] - b2f(h2)), g3 = f2b(vreg[nt][3] - b2f(h3));
                ushort4 uh = {(unsigned short)h0, (unsigned short)h1,
                              (unsigned short)h2, (unsigned short)h3};
                ushort4 ul = {(unsigned short)g0, (unsigned short)g1,
                              (unsigned short)g2, (unsigned short)g3};
                *reinterpret_cast<ushort4*>(&B1h[SWI(nt * 16 + l15, w * 16 + quad * 4)]) = uh;
                *reinterpret_cast<ushort4*>(&B1l[SWI(nt * 16 + l15, w * 16 + quad * 4)]) = ul;
                B2h[SWI(w * 16 + quad * 4 + 0, nt * 16 + l15)] = h0;
                B2h[SWI(w * 16 + quad * 4 + 1, nt * 16 + l15)] = h1;
                B2h[SWI(w * 16 + quad * 4 + 2, nt * 16 + l15)] = h2;
                B2h[SWI(w * 16 + quad * 4 + 3, nt * 16 + l15)] = h3;
                B2l[SWI(w * 16 + quad * 4 + 0, nt * 16 + l15)] = g0;
                B2l[SWI(w * 16 + quad * 4 + 1, nt * 16 + l15)] = g1;
                B2l[SWI(w * 16 + quad * 4 + 2, nt * 16 + l15)] = g2;
                B2l[SWI(w * 16 + quad * 4 + 3, nt * 16 + l15)] = g3;
            }
            __syncthreads();
        }
#undef LOADA
#undef PRODNT
        // write result (fp32 from regs)
#pragma unroll
        for (int nt = 0; nt < 4; nt++)
#pragma unroll
            for (int reg = 0; reg < 4; reg++)
                K2invg[bh * 4096 + (w * 16 + quad * 4 + reg) * 64 + nt * 16 + l15] =
                    vreg[nt][reg];
        return;
    }

    // ================= k3v: W2acc += exp(Qlm (SCALE*K)^T) @ V =================
    short* Kt = reinterpret_cast<short*>(smem);            // B (mm1): [key][dim]
    short* Vt = Kt + 64 * KP;                              // B (mm2): [dim][key]
    short* Eb = Vt + 64 * KP;                              // A (mm2): [landmark][key]
    const int idx = blockIdx.x - 64;
    const int chunk = idx & 31, bh = idx >> 5;             // 32 chunks x 64 bh
    const float4* K4 = reinterpret_cast<const float4*>(K);
    const float4* V4 = reinterpret_cast<const float4*>(V);
    const int dg = t & 15;          // dim-group 0..15 (float4 index)
    const int kr = t >> 4;          // K staging: key row base; V staging: key-group
    const int bhBase = bh * 4096;

    // A fragments straight from Qlm_b (bf16, L2-resident) — no Qs staging
    const bf16x8* Qb = reinterpret_cast<const bf16x8*>(Qlm_b + bh * 4096);
    bf16x8 a0 = Qb[(w * 16 + l15) * 8 + quad];
    bf16x8 a1 = Qb[(w * 16 + l15) * 8 + quad + 4];

    f32x4 oacc[4];
    float rsum[4];
#pragma unroll
    for (int nt = 0; nt < 4; nt++) { oacc[nt] = (f32x4){0.f, 0.f, 0.f, 0.f}; rsum[nt] = 0.f; }

    const int sb0 = chunk * 128;
    for (int tile = 0; tile < 2; tile++) {
        const int sb = sb0 + tile * 64;
        __syncthreads();   // prev tile's MFMA done reading Kt/Vt
        // ---- stage K (scaled, row-major): rows kr+16n at dim-group dg ----
#pragma unroll
        for (int n = 0; n < 4; n++) {
            float4 kk = K4[(bhBase + sb + kr + 16 * n) * 16 + dg];
            ushort4 uk = { (unsigned short)f2b(SCALE * kk.x), (unsigned short)f2b(SCALE * kk.y),
                           (unsigned short)f2b(SCALE * kk.z), (unsigned short)f2b(SCALE * kk.w) };
            *reinterpret_cast<ushort4*>(&Kt[(kr + 16 * n) * KP + dg * 4]) = uk;
        }
        // ---- stage V^T: thread owns keys kr*4..+3 at dims dg*4..+3 ----
        {
            float4 pv0 = V4[(bhBase + sb + kr * 4 + 0) * 16 + dg];
            float4 pv1 = V4[(bhBase + sb + kr * 4 + 1) * 16 + dg];
            float4 pv2 = V4[(bhBase + sb + kr * 4 + 2) * 16 + dg];
            float4 pv3 = V4[(bhBase + sb + kr * 4 + 3) * 16 + dg];
            ushort4 u0 = { (unsigned short)f2b(pv0.x), (unsigned short)f2b(pv1.x),
                           (unsigned short)f2b(pv2.x), (unsigned short)f2b(pv3.x) };
            ushort4 u1 = { (unsigned short)f2b(pv0.y), (unsigned short)f2b(pv1.y),
                           (unsigned short)f2b(pv2.y), (unsigned short)f2b(pv3.y) };
            ushort4 u2 = { (unsigned short)f2b(pv0.z), (unsigned short)f2b(pv1.z),
                           (unsigned short)f2b(pv2.z), (unsigned short)f2b(pv3.z) };
            ushort4 u3 = { (unsigned short)f2b(pv0.w), (unsigned short)f2b(pv1.w),
                           (unsigned short)f2b(pv2.w), (unsigned short)f2b(pv3.w) };
            *reinterpret_cast<ushort4*>(&Vt[(dg * 4 + 0) * KP + kr * 4]) = u0;
            *reinterpret_cast<ushort4*>(&Vt[(dg * 4 + 1) * KP + kr * 4]) = u1;
            *reinterpret_cast<ushort4*>(&Vt[(dg * 4 + 2) * KP + kr * 4]) = u2;
            *reinterpret_cast<ushort4*>(&Vt[(dg * 4 + 3) * KP + kr * 4]) = u3;
        }
        __syncthreads();
        // matmul1: S[m=16w.., n=key] = Qlm . Kt^T
#pragma unroll
        for (int nt = 0; nt < 4; nt++) {
            bf16x8 b0 = *reinterpret_cast<const bf16x8*>(&Kt[(nt * 16 + l15) * KP + quad * 8]);
            bf16x8 b1 = *reinterpret_cast<const bf16x8*>(&Kt[(nt * 16 + l15) * KP + quad * 8 + 32]);
            f32x4 c = {0.f, 0.f, 0.f, 0.f};
            c = MFMA_BF16(a0, b0, c, 0, 0, 0);
            c = MFMA_BF16(a1, b1, c, 0, 0, 0);
#pragma unroll
            for (int reg = 0; reg < 4; reg++) {
                float e = __expf(c[reg]);
                rsum[reg] += e;
                Eb[(w * 16 + quad * 4 + reg) * KP + nt * 16 + l15] = f2b(e);
            }
        }
        // matmul2: oacc += E . Vt^T   (wave reads only its own E rows -> no barrier)
        bf16x8 e0 = *reinterpret_cast<const bf16x8*>(&Eb[(w * 16 + l15) * KP + quad * 8]);
        bf16x8 e1 = *reinterpret_cast<const bf16x8*>(&Eb[(w * 16 + l15) * KP + quad * 8 + 32]);
#pragma unroll
        for (int nt = 0; nt < 4; nt++) {
            bf16x8 b0 = *reinterpret_cast<const bf16x8*>(&Vt[(nt * 16 + l15) * KP + quad * 8]);
            bf16x8 b1 = *reinterpret_cast<const bf16x8*>(&Vt[(nt * 16 + l15) * KP + quad * 8 + 32]);
            oacc[nt] = MFMA_BF16(e0, b0, oacc[nt], 0, 0, 0);
            oacc[nt] = MFMA_BF16(e1, b1, oacc[nt], 0, 0, 0);
        }
    }
    // reduce rowsums over the 16 lanes of each quad
#pragma unroll
    for (int reg = 0; reg < 4; reg++) {
        float s = rsum[reg];
        s += __shfl_xor(s, 1); s += __shfl_xor(s, 2);
        s += __shfl_xor(s, 4); s += __shfl_xor(s, 8);
        rsum[reg] = s;
    }
    const int row0 = w * 16 + quad * 4;
    if (l15 == 0) {
#pragma unroll
        for (int reg = 0; reg < 4; reg++)
            atomicAdd(&rowsum3[bh * 64 + row0 + reg], rsum[reg]);
    }
#pragma unroll
    for (int nt = 0; nt < 4; nt++)
#pragma unroll
        for (int reg = 0; reg < 4; reg++)
            atomicAdd(&W2acc[(bh * 64 + row0 + reg) * 64 + nt * 16 + l15], oacc[nt][reg]);
}

// ---------- E: W = inv(K2) @ (W2acc / rowsum3), emitted as bf16 hi/lo TRANSPOSED ----------
__global__ __launch_bounds__(256) void wmid_kernel(const float* __restrict__ K2invg,
                                                   const float* __restrict__ W2acc,
                                                   const float* __restrict__ rowsum3,
                                                   short* __restrict__ Wth,
                                                   short* __restrict__ Wtl) {
    __shared__ float I1[64 * PAD], W2[64 * PAD];
    const int bh = blockIdx.x, t = threadIdx.x;
#pragma unroll
    for (int n = 0; n < 16; n++) {
        int f = t + n * 256;
        int r = f >> 6;
        I1[r * PAD + (f & 63)] = K2invg[bh * 4096 + f];
        W2[r * PAD + (f & 63)] = W2acc[bh * 4096 + f] / rowsum3[bh * 64 + r];
    }
    __syncthreads();
    const int i = t >> 2, j0 = (t & 3) * 16;
    float acc[16];
#pragma unroll
    for (int u = 0; u < 16; u++) acc[u] = 0.f;
    for (int k = 0; k < 64; k++) fma16(acc, I1[i * PAD + k], W2 + k * PAD + j0);
    // transposed bf16 hi/lo store: Wth/Wtl[bh][dim][lm]
#pragma unroll
    for (int u = 0; u < 16; u++) {
        float wv = acc[u];
        short hi = f2b(wv);
        short lo = f2b(wv - b2f(hi));
        Wth[bh * 4096 + (j0 + u) * 64 + i] = hi;
        Wtl[bh * 4096 + (j0 + u) * 64 + i] = lo;
    }
}

// ---------- F (MFMA): X = softmax((SCALE*Q) Klm^T) @ W ----------
//            Barrier-free: A-frags from Q (global), B-frags from bf16 L2-resident
//            operands. LDS = Eb only (9 KB) -> high occupancy, pure streaming.
__global__ __launch_bounds__(256) void final_mfma(const float* __restrict__ Q,
                                                  const short* __restrict__ Klm_b,
                                                  const short* __restrict__ Wth,
                                                  const short* __restrict__ Wtl,
                                                  float* __restrict__ out) {
    __shared__ short Eb[64 * KP];   // A (mm2): [seqrow][landmark] — wave-private rows
    const int sc = blockIdx.x, bh = blockIdx.y, t = threadIdx.x;
    const int w = t >> 6, lane = t & 63, quad = lane >> 4, l15 = lane & 15;
    const int s0 = sc * 64;
    const int row = w * 16 + l15;

    // Q fragment loads (issued first, fly under everything below)
    const float* qrow = Q + ((size_t)bh * 4096 + s0 + row) * 64 + quad * 8;
    float4 qa = *reinterpret_cast<const float4*>(qrow);
    float4 qb = *reinterpret_cast<const float4*>(qrow + 4);
    float4 qc = *reinterpret_cast<const float4*>(qrow + 32);
    float4 qd = *reinterpret_cast<const float4*>(qrow + 36);

    // B-fragment base pointers (bf16, L2-resident: 8 KB per bh each)
    const bf16x8* Kb = reinterpret_cast<const bf16x8*>(Klm_b + bh * 4096);  // [lm][dim]
    const bf16x8* Hb = reinterpret_cast<const bf16x8*>(Wth + bh * 4096);    // [dim][lm]
    const bf16x8* Lb = reinterpret_cast<const bf16x8*>(Wtl + bh * 4096);    // [dim][lm]

    // build A fragments (scaled, bf16)
    bf16x8 a0, a1;
    a0[0] = f2b(SCALE * qa.x); a0[1] = f2b(SCALE * qa.y);
    a0[2] = f2b(SCALE * qa.z); a0[3] = f2b(SCALE * qa.w);
    a0[4] = f2b(SCALE * qb.x); a0[5] = f2b(SCALE * qb.y);
    a0[6] = f2b(SCALE * qb.z); a0[7] = f2b(SCALE * qb.w);
    a1[0] = f2b(SCALE * qc.x); a1[1] = f2b(SCALE * qc.y);
    a1[2] = f2b(SCALE * qc.z); a1[3] = f2b(SCALE * qc.w);
    a1[4] = f2b(SCALE * qd.x); a1[5] = f2b(SCALE * qd.y);
    a1[6] = f2b(SCALE * qd.z); a1[7] = f2b(SCALE * qd.w);

    // mm1: S = Q . Klm^T ; exp ; rowsum ; Eb
    float rsum[4] = {0.f, 0.f, 0.f, 0.f};
#pragma unroll
    for (int nt = 0; nt < 4; nt++) {
        bf16x8 b0 = Kb[(nt * 16 + l15) * 8 + quad];
        bf16x8 b1 = Kb[(nt * 16 + l15) * 8 + quad + 4];
        f32x4 c = {0.f, 0.f, 0.f, 0.f};
        c = MFMA_BF16(a0, b0, c, 0, 0, 0);
        c = MFMA_BF16(a1, b1, c, 0, 0, 0);
#pragma unroll
        for (int reg = 0; reg < 4; reg++) {
            float e = __expf(c[reg]);
            rsum[reg] += e;
            Eb[(w * 16 + quad * 4 + reg) * KP + nt * 16 + l15] = f2b(e);
        }
    }
#pragma unroll
    for (int reg = 0; reg < 4; reg++) {
        float s = rsum[reg];
        s += __shfl_xor(s, 1); s += __shfl_xor(s, 2);
        s += __shfl_xor(s, 4); s += __shfl_xor(s, 8);
        rsum[reg] = 1.0f / s;
    }
    // mm2: X = Eb . (Wh + Wl)   (wave reads only its own Eb rows -> no barrier)
    bf16x8 e0 = *reinterpret_cast<const bf16x8*>(&Eb[row * KP + quad * 8]);
    bf16x8 e1 = *reinterpret_cast<const bf16x8*>(&Eb[row * KP + quad * 8 + 32]);
    const int row0 = w * 16 + quad * 4;
#pragma unroll
    for (int nt = 0; nt < 4; nt++) {
        bf16x8 bh0 = Hb[(nt * 16 + l15) * 8 + quad];
        bf16x8 bh1 = Hb[(nt * 16 + l15) * 8 + quad + 4];
        bf16x8 bl0 = Lb[(nt * 16 + l15) * 8 + quad];
        bf16x8 bl1 = Lb[(nt * 16 + l15) * 8 + quad + 4];
        f32x4 c = {0.f, 0.f, 0.f, 0.f};
        c = MFMA_BF16(e0, bh0, c, 0, 0, 0);
        c = MFMA_BF16(e1, bh1, c, 0, 0, 0);
        c = MFMA_BF16(e0, bl0, c, 0, 0, 0);
        c = MFMA_BF16(e1, bl1, c, 0, 0, 0);
#pragma unroll
        for (int reg = 0; reg < 4; reg++)
            out[((size_t)bh * 4096 + s0 + row0 + reg) * 64 + nt * 16 + l15] = c[reg] * rsum[reg];
    }
}

extern "C" void kernel_launch(void* const* d_in, const int* in_sizes, int n_in,
                              void* d_out, int out_size, void* d_ws, size_t ws_size,
                              hipStream_t stream) {
    const float* Q = (const float*)d_in[0];
    const float* K = (const float*)d_in[1];
    const float* V = (const float*)d_in[2];
    float* out = (float*)d_out;
    float* ws = (float*)d_ws;

    float* Qlm     = ws;                                   // 262144 fp32
    float* Klm     = ws + 262144;                          // 262144 fp32
    float* K2      = ws + 524288;                          // 262144 fp32
    float* K2inv   = ws + 786432;                          // 262144 fp32
    short* Wth     = (short*)(ws + 1048576);               // 262144 bf16
    short* Wtl     = (short*)(ws + 1179648);               // 262144 bf16
    float* W2acc   = ws + 1310720;                         // 262144 fp32, zeroed
    float* rowsum3 = ws + 1572864;                         // 4096 fp32, zeroed
    unsigned* colmax = (unsigned*)(ws + 1576960);          // 1, zeroed
    short* Qlm_b   = (short*)(ws + 1576964);               // 262144 bf16
    short* Klm_b   = (short*)(ws + 1708036);               // 262144 bf16

    hipMemsetAsync(W2acc, 0, (262144 + 4096 + 1) * sizeof(float), stream);

    pool_kernel<<<4096, 256, 0, stream>>>(Q, K, Qlm, Klm, Qlm_b, Klm_b);
    k2_kernel<<<64, 256, 0, stream>>>(Qlm, Klm, K2, colmax);
    // blocks 0..63: MFMA Newton-Schulz inverse; blocks 64..2111: k3v
    fused_inv_k3v<<<2112, 256, 0, stream>>>(Qlm_b, K, V, W2acc, rowsum3, K2, colmax, K2inv);
    wmid_kernel<<<64, 256, 0, stream>>>(K2inv, W2acc, rowsum3, Wth, Wtl);
    final_mfma<<<dim3(64, 64), 256, 0, stream>>>(Q, Klm_b, Wth, Wtl, out);
}

// Round 6
// 299.520 us; speedup vs baseline: 1.1271x; 1.0473x over previous
//
#include <hip/hip_runtime.h>
#include <hip/hip_bf16.h>

#define KP  72            // bf16 LDS pitch: 144 B row
#define SCALE 0.35355339059327379f

typedef __attribute__((ext_vector_type(8))) short bf16x8;
typedef __attribute__((ext_vector_type(4))) float f32x4;
#define MFMA_BF16 __builtin_amdgcn_mfma_f32_16x16x32_bf16

__device__ __forceinline__ short f2b(float f) {          // fp32 -> bf16 RNE
    unsigned u = __float_as_uint(f);
    u += 0x7fff + ((u >> 16) & 1);
    return (short)(u >> 16);
}
__device__ __forceinline__ float b2f(short h) {
    return __uint_as_float(((unsigned)(unsigned short)h) << 16);
}

// swizzled short-index into a [64][64]-short (pitch 64) LDS tile:
// byte = row*128 + colS*2, XOR'd with (row&7)<<4 -> b128 reads 2-way conflict only
__device__ __forceinline__ int SWI(int row, int colS) {
    return (((row << 7) + (colS << 1)) ^ ((row & 7) << 4)) >> 1;
}

// ---------- A: landmark pooling -> Qlm/Klm hi+lo bf16, pre-scaled by SCALE/64 ----------
__global__ __launch_bounds__(256) void pool_kernel(const float* __restrict__ Q,
                                                   const float* __restrict__ K,
                                                   short* __restrict__ Qlm_bh,
                                                   short* __restrict__ Qlm_bl,
                                                   short* __restrict__ Klm_bh,
                                                   short* __restrict__ Klm_bl) {
    __shared__ float4 red[256];
    const int blk = blockIdx.x;
    const int t = threadIdx.x;
    const int d4 = t & 15;
    const int rg = t >> 4;
    const float4* Q4 = reinterpret_cast<const float4*>(Q);
    const float4* K4 = reinterpret_cast<const float4*>(K);

    float4 sQ = {0.f, 0.f, 0.f, 0.f}, sK = {0.f, 0.f, 0.f, 0.f};
#pragma unroll
    for (int rr = 0; rr < 4; rr++) {
        int row = blk * 64 + rg * 4 + rr;
        int off4 = (row << 4) + d4;
        float4 q = Q4[off4], k = K4[off4];
        sQ.x += q.x; sQ.y += q.y; sQ.z += q.z; sQ.w += q.w;
        sK.x += k.x; sK.y += k.y; sK.z += k.z; sK.w += k.w;
    }
    const float c = SCALE * (1.0f / 64.0f);
    red[t] = sQ;
    __syncthreads();
    if (t < 16) {
        float4 s = {0.f, 0.f, 0.f, 0.f};
#pragma unroll
        for (int g = 0; g < 16; g++) {
            float4 v = red[g * 16 + t];
            s.x += v.x; s.y += v.y; s.z += v.z; s.w += v.w;
        }
        s.x *= c; s.y *= c; s.z *= c; s.w *= c;
        short h0 = f2b(s.x), h1 = f2b(s.y), h2 = f2b(s.z), h3 = f2b(s.w);
        ushort4 uh = {(unsigned short)h0, (unsigned short)h1,
                      (unsigned short)h2, (unsigned short)h3};
        ushort4 ul = {(unsigned short)f2b(s.x - b2f(h0)), (unsigned short)f2b(s.y - b2f(h1)),
                      (unsigned short)f2b(s.z - b2f(h2)), (unsigned short)f2b(s.w - b2f(h3))};
        *reinterpret_cast<ushort4*>(&Qlm_bh[blk * 64 + t * 4]) = uh;
        *reinterpret_cast<ushort4*>(&Qlm_bl[blk * 64 + t * 4]) = ul;
    }
    __syncthreads();
    red[t] = sK;
    __syncthreads();
    if (t < 16) {
        float4 s = {0.f, 0.f, 0.f, 0.f};
#pragma unroll
        for (int g = 0; g < 16; g++) {
            float4 v = red[g * 16 + t];
            s.x += v.x; s.y += v.y; s.z += v.z; s.w += v.w;
        }
        s.x *= c; s.y *= c; s.z *= c; s.w *= c;
        short h0 = f2b(s.x), h1 = f2b(s.y), h2 = f2b(s.z), h3 = f2b(s.w);
        ushort4 uh = {(unsigned short)h0, (unsigned short)h1,
                      (unsigned short)h2, (unsigned short)h3};
        ushort4 ul = {(unsigned short)f2b(s.x - b2f(h0)), (unsigned short)f2b(s.y - b2f(h1)),
                      (unsigned short)f2b(s.z - b2f(h2)), (unsigned short)f2b(s.w - b2f(h3))};
        *reinterpret_cast<ushort4*>(&Klm_bh[blk * 64 + t * 4]) = uh;
        *reinterpret_cast<ushort4*>(&Klm_bl[blk * 64 + t * 4]) = ul;
    }
}

// ---------- B: K2 = softmax(Qlm Klm^T) via hi/lo MFMA; wave-parallel softmax ----------
__global__ __launch_bounds__(256) void k2_kernel(const short* __restrict__ Qlm_bh,
                                                 const short* __restrict__ Qlm_bl,
                                                 const short* __restrict__ Klm_bh,
                                                 const short* __restrict__ Klm_bl,
                                                 float* __restrict__ K2g,
                                                 unsigned* __restrict__ colmax) {
    __shared__ float csum[16 * 64];
    const int bh = blockIdx.x, t = threadIdx.x;
    const int w = t >> 6, lane = t & 63, quad = lane >> 4, l15 = lane & 15;

    const bf16x8* Ah = reinterpret_cast<const bf16x8*>(Qlm_bh + bh * 4096);
    const bf16x8* Al = reinterpret_cast<const bf16x8*>(Qlm_bl + bh * 4096);
    const bf16x8* Bh = reinterpret_cast<const bf16x8*>(Klm_bh + bh * 4096);
    const bf16x8* Bl = reinterpret_cast<const bf16x8*>(Klm_bl + bh * 4096);
    bf16x8 ah0 = Ah[(w * 16 + l15) * 8 + quad], ah1 = Ah[(w * 16 + l15) * 8 + quad + 4];
    bf16x8 al0 = Al[(w * 16 + l15) * 8 + quad], al1 = Al[(w * 16 + l15) * 8 + quad + 4];

    f32x4 c[4];
#pragma unroll
    for (int nt = 0; nt < 4; nt++) {
        bf16x8 bh0 = Bh[(nt * 16 + l15) * 8 + quad], bh1 = Bh[(nt * 16 + l15) * 8 + quad + 4];
        bf16x8 bl0 = Bl[(nt * 16 + l15) * 8 + quad], bl1 = Bl[(nt * 16 + l15) * 8 + quad + 4];
        f32x4 cc = {0.f, 0.f, 0.f, 0.f};
        cc = MFMA_BF16(ah0, bh0, cc, 0, 0, 0); cc = MFMA_BF16(ah1, bh1, cc, 0, 0, 0);
        cc = MFMA_BF16(ah0, bl0, cc, 0, 0, 0); cc = MFMA_BF16(ah1, bl1, cc, 0, 0, 0);
        cc = MFMA_BF16(al0, bh0, cc, 0, 0, 0); cc = MFMA_BF16(al1, bh1, cc, 0, 0, 0);
        c[nt] = cc;
    }
    // row softmax: row = w*16+quad*4+reg lives across 16 lanes (l15) x 4 nt
    float m[4] = {-1e30f, -1e30f, -1e30f, -1e30f};
#pragma unroll
    for (int nt = 0; nt < 4; nt++)
#pragma unroll
        for (int reg = 0; reg < 4; reg++) m[reg] = fmaxf(m[reg], c[nt][reg]);
#pragma unroll
    for (int reg = 0; reg < 4; reg++) {
        float v = m[reg];
        v = fmaxf(v, __shfl_xor(v, 1)); v = fmaxf(v, __shfl_xor(v, 2));
        v = fmaxf(v, __shfl_xor(v, 4)); v = fmaxf(v, __shfl_xor(v, 8));
        m[reg] = v;
    }
    float e[4][4];
    float rs[4] = {0.f, 0.f, 0.f, 0.f};
#pragma unroll
    for (int nt = 0; nt < 4; nt++)
#pragma unroll
        for (int reg = 0; reg < 4; reg++) {
            float ev = __expf(c[nt][reg] - m[reg]);
            e[nt][reg] = ev; rs[reg] += ev;
        }
#pragma unroll
    for (int reg = 0; reg < 4; reg++) {
        float v = rs[reg];
        v += __shfl_xor(v, 1); v += __shfl_xor(v, 2);
        v += __shfl_xor(v, 4); v += __shfl_xor(v, 8);
        rs[reg] = 1.0f / v;
    }
    float ps[4] = {0.f, 0.f, 0.f, 0.f};
#pragma unroll
    for (int nt = 0; nt < 4; nt++) {
#pragma unroll
        for (int reg = 0; reg < 4; reg++) {
            float p = e[nt][reg] * rs[reg];
            K2g[bh * 4096 + (w * 16 + quad * 4 + reg) * 64 + nt * 16 + l15] = p;
            ps[nt] += p;
        }
        csum[(w * 4 + quad) * 64 + nt * 16 + l15] = ps[nt];
    }
    __syncthreads();
    if (t < 64) {
        float s = 0.f;
#pragma unroll
        for (int i = 0; i < 16; i++) s += csum[i * 64 + t];
        atomicMax(colmax, __float_as_uint(s));
    }
}

// ---------- C+D fused: blocks 0..63 Newton-Schulz inverse (MFMA hi/lo bf16);
//            blocks 64..2111 k3v. ----------
__global__ __launch_bounds__(256) void fused_inv_k3v(const short* __restrict__ Qlm_bh,
                                                     const float* __restrict__ K,
                                                     const float* __restrict__ V,
                                                     float* __restrict__ W2acc,
                                                     float* __restrict__ rowsum3,
                                                     const float* __restrict__ K2g,
                                                     const unsigned* __restrict__ colmax,
                                                     float* __restrict__ K2invg) {
    // inverse: 8 x [64][64]-short swizzled tiles = 64 KB; k3v: 3 x 64*KP = 27.6 KB
    __shared__ __align__(16) char smem[65536];
    const int t = threadIdx.x;
    const int w = t >> 6, lane = t & 63, quad = lane >> 4, l15 = lane & 15;

    if (blockIdx.x < 64) {
        // ===== Newton-Schulz inverse, MFMA bf16 hi/lo (4-term, ~2^-17 rel) ======
        short* Krh = reinterpret_cast<short*>(smem);       // K2 hi (row-major)
        short* Krl = Krh + 4096;                           // K2 lo
        short* Ath = Krl + 4096;                           // A^T hi
        short* Atl = Ath + 4096;
        short* B1h = Atl + 4096;                           // V^T / P / V'^T
        short* B1l = B1h + 4096;
        short* B2h = B1l + 4096;                           // V / Q2 / V'
        short* B2l = B2h + 4096;
        const int bh = blockIdx.x;
        const float scv = 1.0f / __uint_as_float(*colmax);
        const float* Kg = K2g + bh * 4096;

        // ---- stage Kr (hi/lo), B1 = scv*K2 (= V0^T), B2 = scv*K2^T (= V0) ----
#pragma unroll
        for (int n = 0; n < 4; n++) {
            int f4 = t + n * 256;
            int r = f4 >> 4, c0 = (f4 & 15) * 4;
            float4 kk = *reinterpret_cast<const float4*>(Kg + r * 64 + c0);
            short h0 = f2b(kk.x), h1 = f2b(kk.y), h2 = f2b(kk.z), h3 = f2b(kk.w);
            ushort4 uh = {(unsigned short)h0, (unsigned short)h1,
                          (unsigned short)h2, (unsigned short)h3};
            ushort4 ul = {(unsigned short)f2b(kk.x - b2f(h0)), (unsigned short)f2b(kk.y - b2f(h1)),
                          (unsigned short)f2b(kk.z - b2f(h2)), (unsigned short)f2b(kk.w - b2f(h3))};
            *reinterpret_cast<ushort4*>(&Krh[SWI(r, c0)]) = uh;
            *reinterpret_cast<ushort4*>(&Krl[SWI(r, c0)]) = ul;
            float s0 = scv * kk.x, s1 = scv * kk.y, s2 = scv * kk.z, s3 = scv * kk.w;
            short g0 = f2b(s0), g1 = f2b(s1), g2 = f2b(s2), g3 = f2b(s3);
            ushort4 vh = {(unsigned short)g0, (unsigned short)g1,
                          (unsigned short)g2, (unsigned short)g3};
            ushort4 vl = {(unsigned short)f2b(s0 - b2f(g0)), (unsigned short)f2b(s1 - b2f(g1)),
                          (unsigned short)f2b(s2 - b2f(g2)), (unsigned short)f2b(s3 - b2f(g3))};
            *reinterpret_cast<ushort4*>(&B1h[SWI(r, c0)]) = vh;
            *reinterpret_cast<ushort4*>(&B1l[SWI(r, c0)]) = vl;
            float t0 = scv * Kg[(c0 + 0) * 64 + r];
            float t1 = scv * Kg[(c0 + 1) * 64 + r];
            float t2 = scv * Kg[(c0 + 2) * 64 + r];
            float t3 = scv * Kg[(c0 + 3) * 64 + r];
            short e0 = f2b(t0), e1 = f2b(t1), e2 = f2b(t2), e3 = f2b(t3);
            ushort4 th = {(unsigned short)e0, (unsigned short)e1,
                          (unsigned short)e2, (unsigned short)e3};
            ushort4 tl = {(unsigned short)f2b(t0 - b2f(e0)), (unsigned short)f2b(t1 - b2f(e1)),
                          (unsigned short)f2b(t2 - b2f(e2)), (unsigned short)f2b(t3 - b2f(e3))};
            *reinterpret_cast<ushort4*>(&B2h[SWI(r, c0)]) = th;
            *reinterpret_cast<ushort4*>(&B2l[SWI(r, c0)]) = tl;
        }
        // V in fp32 registers: vreg[nt][reg] = V0[w*16+quad*4+reg][nt*16+l15]
        float vreg[4][4];
#pragma unroll
        for (int nt = 0; nt < 4; nt++) {
            float4 vv = *reinterpret_cast<const float4*>(
                Kg + (nt * 16 + l15) * 64 + w * 16 + quad * 4);
            vreg[nt][0] = scv * vv.x; vreg[nt][1] = scv * vv.y;
            vreg[nt][2] = scv * vv.z; vreg[nt][3] = scv * vv.w;
        }
        __syncthreads();

#define LOADA(Lh, Ll) \
        bf16x8 ah0 = *reinterpret_cast<const bf16x8*>(&Lh[SWI(w * 16 + l15, quad * 8)]); \
        bf16x8 ah1 = *reinterpret_cast<const bf16x8*>(&Lh[SWI(w * 16 + l15, quad * 8 + 32)]); \
        bf16x8 al0 = *reinterpret_cast<const bf16x8*>(&Ll[SWI(w * 16 + l15, quad * 8)]); \
        bf16x8 al1 = *reinterpret_cast<const bf16x8*>(&Ll[SWI(w * 16 + l15, quad * 8 + 32)]);
#define PRODNT(Bh, Bl, nt, c) { \
        bf16x8 bh0 = *reinterpret_cast<const bf16x8*>(&Bh[SWI(nt * 16 + l15, quad * 8)]); \
        bf16x8 bh1 = *reinterpret_cast<const bf16x8*>(&Bh[SWI(nt * 16 + l15, quad * 8 + 32)]); \
        bf16x8 bl0 = *reinterpret_cast<const bf16x8*>(&Bl[SWI(nt * 16 + l15, quad * 8)]); \
        bf16x8 bl1 = *reinterpret_cast<const bf16x8*>(&Bl[SWI(nt * 16 + l15, quad * 8 + 32)]); \
        c = MFMA_BF16(ah0, bh0, c, 0, 0, 0); c = MFMA_BF16(ah1, bh1, c, 0, 0, 0); \
        c = MFMA_BF16(ah0, bl0, c, 0, 0, 0); c = MFMA_BF16(ah1, bl1, c, 0, 0, 0); \
        c = MFMA_BF16(al0, bh0, c, 0, 0, 0); c = MFMA_BF16(al1, bh1, c, 0, 0, 0); \
        c = MFMA_BF16(al0, bl0, c, 0, 0, 0); c = MFMA_BF16(al1, bl1, c, 0, 0, 0); }

        for (int iter = 0; iter < 6; iter++) {
            // M1: A = K·V  (B = B1 = V^T) -> write A^T hi/lo
            {
                LOADA(Krh, Krl)
#pragma unroll
                for (int nt = 0; nt < 4; nt++) {
                    f32x4 c = {0.f, 0.f, 0.f, 0.f};
                    PRODNT(B1h, B1l, nt, c)
                    short h0 = f2b(c[0]), h1 = f2b(c[1]), h2 = f2b(c[2]), h3 = f2b(c[3]);
                    ushort4 uh = {(unsigned short)h0, (unsigned short)h1,
                                  (unsigned short)h2, (unsigned short)h3};
                    ushort4 ul = {(unsigned short)f2b(c[0] - b2f(h0)),
                                  (unsigned short)f2b(c[1] - b2f(h1)),
                                  (unsigned short)f2b(c[2] - b2f(h2)),
                                  (unsigned short)f2b(c[3] - b2f(h3))};
                    *reinterpret_cast<ushort4*>(&Ath[SWI(nt * 16 + l15, w * 16 + quad * 4)]) = uh;
                    *reinterpret_cast<ushort4*>(&Atl[SWI(nt * 16 + l15, w * 16 + quad * 4)]) = ul;
                }
            }
            __syncthreads();
            // M2: P = V·A (LHS = B2 own rows, B = A^T) -> p regs + P rows into B1
            float p[4][4];
            {
                LOADA(B2h, B2l)
#pragma unroll
                for (int nt = 0; nt < 4; nt++) {
                    f32x4 c = {0.f, 0.f, 0.f, 0.f};
                    PRODNT(Ath, Atl, nt, c)
#pragma unroll
                    for (int reg = 0; reg < 4; reg++) {
                        p[nt][reg] = c[reg];
                        short hh = f2b(c[reg]);
                        B1h[SWI(w * 16 + quad * 4 + reg, nt * 16 + l15)] = hh;
                        B1l[SWI(w * 16 + quad * 4 + reg, nt * 16 + l15)] = f2b(c[reg] - b2f(hh));
                    }
                }
            }
            __syncthreads();
            // M3: Q2 = P·A (LHS = B1 own rows) -> q regs + Q2 rows into B2
            float q[4][4];
            {
                LOADA(B1h, B1l)
#pragma unroll
                for (int nt = 0; nt < 4; nt++) {
                    f32x4 c = {0.f, 0.f, 0.f, 0.f};
                    PRODNT(Ath, Atl, nt, c)
#pragma unroll
                    for (int reg = 0; reg < 4; reg++) {
                        q[nt][reg] = c[reg];
                        short hh = f2b(c[reg]);
                        B2h[SWI(w * 16 + quad * 4 + reg, nt * 16 + l15)] = hh;
                        B2l[SWI(w * 16 + quad * 4 + reg, nt * 16 + l15)] = f2b(c[reg] - b2f(hh));
                    }
                }
            }
            __syncthreads();
            // M4: R = Q2·A (LHS = B2 own rows); combo in fp32 regs; publish V'
            {
                LOADA(B2h, B2l)
#pragma unroll
                for (int nt = 0; nt < 4; nt++) {
                    f32x4 c = {0.f, 0.f, 0.f, 0.f};
                    PRODNT(Ath, Atl, nt, c)
#pragma unroll
                    for (int reg = 0; reg < 4; reg++)
                        vreg[nt][reg] = 0.25f * (13.f * vreg[nt][reg] - 15.f * p[nt][reg]
                                                 + 7.f * q[nt][reg] - c[reg]);
                }
            }
            // write V' rows into B2 (own rows) and V'^T into B1 (hi/lo)
#pragma unroll
            for (int nt = 0; nt < 4; nt++) {
                short h0 = f2b(vreg[nt][0]), h1 = f2b(vreg[nt][1]);
                short h2 = f2b(vreg[nt][2]), h3 = f2b(vreg[nt][3]);
                short g0 = f2b(vreg[nt][0] - b2f(h0)), g1 = f2b(vreg[nt][1] - b2f(h1));
                short g2 = f2b(vreg[nt][2] - b2f(h2)), g3 = f2b(vreg[nt][3] - b2f(h3));
                ushort4 uh = {(unsigned short)h0, (unsigned short)h1,
                              (unsigned short)h2, (unsigned short)h3};
                ushort4 ul = {(unsigned short)g0, (unsigned short)g1,
                              (unsigned short)g2, (unsigned short)g3};
                *reinterpret_cast<ushort4*>(&B1h[SWI(nt * 16 + l15, w * 16 + quad * 4)]) = uh;
                *reinterpret_cast<ushort4*>(&B1l[SWI(nt * 16 + l15, w * 16 + quad * 4)]) = ul;
                B2h[SWI(w * 16 + quad * 4 + 0, nt * 16 + l15)] = h0;
                B2h[SWI(w * 16 + quad * 4 + 1, nt * 16 + l15)] = h1;
                B2h[SWI(w * 16 + quad * 4 + 2, nt * 16 + l15)] = h2;
                B2h[SWI(w * 16 + quad * 4 + 3, nt * 16 + l15)] = h3;
                B2l[SWI(w * 16 + quad * 4 + 0, nt * 16 + l15)] = g0;
                B2l[SWI(w * 16 + quad * 4 + 1, nt * 16 + l15)] = g1;
                B2l[SWI(w * 16 + quad * 4 + 2, nt * 16 + l15)] = g2;
                B2l[SWI(w * 16 + quad * 4 + 3, nt * 16 + l15)] = g3;
            }
            __syncthreads();
        }
#undef LOADA
#undef PRODNT
        // write result (fp32 from regs)
#pragma unroll
        for (int nt = 0; nt < 4; nt++)
#pragma unroll
            for (int reg = 0; reg < 4; reg++)
                K2invg[bh * 4096 + (w * 16 + quad * 4 + reg) * 64 + nt * 16 + l15] =
                    vreg[nt][reg];
        return;
    }

    // ================= k3v: W2acc += exp(Qlm (SCALE*K)^T) @ V =================
    short* Kt = reinterpret_cast<short*>(smem);            // B (mm1): [key][dim]
    short* Vt = Kt + 64 * KP;                              // B (mm2): [dim][key]
    short* Eb = Vt + 64 * KP;                              // A (mm2): [landmark][key]
    const int idx = blockIdx.x - 64;
    const int chunk = idx & 31, bh = idx >> 5;             // 32 chunks x 64 bh
    const float4* K4 = reinterpret_cast<const float4*>(K);
    const float4* V4 = reinterpret_cast<const float4*>(V);
    const int dg = t & 15;          // dim-group 0..15 (float4 index)
    const int kr = t >> 4;          // K staging: key row base; V staging: key-group
    const int bhBase = bh * 4096;

    // A fragments straight from Qlm_bh (bf16, L2-resident)
    const bf16x8* Qb = reinterpret_cast<const bf16x8*>(Qlm_bh + bh * 4096);
    bf16x8 a0 = Qb[(w * 16 + l15) * 8 + quad];
    bf16x8 a1 = Qb[(w * 16 + l15) * 8 + quad + 4];

    f32x4 oacc[4];
    float rsum[4];
#pragma unroll
    for (int nt = 0; nt < 4; nt++) { oacc[nt] = (f32x4){0.f, 0.f, 0.f, 0.f}; rsum[nt] = 0.f; }

    const int sb0 = chunk * 128;
    for (int tile = 0; tile < 2; tile++) {
        const int sb = sb0 + tile * 64;
        __syncthreads();   // prev tile's MFMA done reading Kt/Vt
        // ---- stage K (scaled, row-major): rows kr+16n at dim-group dg ----
#pragma unroll
        for (int n = 0; n < 4; n++) {
            float4 kk = K4[(bhBase + sb + kr + 16 * n) * 16 + dg];
            ushort4 uk = { (unsigned short)f2b(SCALE * kk.x), (unsigned short)f2b(SCALE * kk.y),
                           (unsigned short)f2b(SCALE * kk.z), (unsigned short)f2b(SCALE * kk.w) };
            *reinterpret_cast<ushort4*>(&Kt[(kr + 16 * n) * KP + dg * 4]) = uk;
        }
        // ---- stage V^T: thread owns keys kr*4..+3 at dims dg*4..+3 ----
        {
            float4 pv0 = V4[(bhBase + sb + kr * 4 + 0) * 16 + dg];
            float4 pv1 = V4[(bhBase + sb + kr * 4 + 1) * 16 + dg];
            float4 pv2 = V4[(bhBase + sb + kr * 4 + 2) * 16 + dg];
            float4 pv3 = V4[(bhBase + sb + kr * 4 + 3) * 16 + dg];
            ushort4 u0 = { (unsigned short)f2b(pv0.x), (unsigned short)f2b(pv1.x),
                           (unsigned short)f2b(pv2.x), (unsigned short)f2b(pv3.x) };
            ushort4 u1 = { (unsigned short)f2b(pv0.y), (unsigned short)f2b(pv1.y),
                           (unsigned short)f2b(pv2.y), (unsigned short)f2b(pv3.y) };
            ushort4 u2 = { (unsigned short)f2b(pv0.z), (unsigned short)f2b(pv1.z),
                           (unsigned short)f2b(pv2.z), (unsigned short)f2b(pv3.z) };
            ushort4 u3 = { (unsigned short)f2b(pv0.w), (unsigned short)f2b(pv1.w),
                           (unsigned short)f2b(pv2.w), (unsigned short)f2b(pv3.w) };
            *reinterpret_cast<ushort4*>(&Vt[(dg * 4 + 0) * KP + kr * 4]) = u0;
            *reinterpret_cast<ushort4*>(&Vt[(dg * 4 + 1) * KP + kr * 4]) = u1;
            *reinterpret_cast<ushort4*>(&Vt[(dg * 4 + 2) * KP + kr * 4]) = u2;
            *reinterpret_cast<ushort4*>(&Vt[(dg * 4 + 3) * KP + kr * 4]) = u3;
        }
        __syncthreads();
        // matmul1: S[m=16w.., n=key] = Qlm . Kt^T
#pragma unroll
        for (int nt = 0; nt < 4; nt++) {
            bf16x8 b0 = *reinterpret_cast<const bf16x8*>(&Kt[(nt * 16 + l15) * KP + quad * 8]);
            bf16x8 b1 = *reinterpret_cast<const bf16x8*>(&Kt[(nt * 16 + l15) * KP + quad * 8 + 32]);
            f32x4 c = {0.f, 0.f, 0.f, 0.f};
            c = MFMA_BF16(a0, b0, c, 0, 0, 0);
            c = MFMA_BF16(a1, b1, c, 0, 0, 0);
#pragma unroll
            for (int reg = 0; reg < 4; reg++) {
                float e = __expf(c[reg]);
                rsum[reg] += e;
                Eb[(w * 16 + quad * 4 + reg) * KP + nt * 16 + l15] = f2b(e);
            }
        }
        // matmul2: oacc += E . Vt^T   (wave reads only its own E rows -> no barrier)
        bf16x8 e0 = *reinterpret_cast<const bf16x8*>(&Eb[(w * 16 + l15) * KP + quad * 8]);
        bf16x8 e1 = *reinterpret_cast<const bf16x8*>(&Eb[(w * 16 + l15) * KP + quad * 8 + 32]);
#pragma unroll
        for (int nt = 0; nt < 4; nt++) {
            bf16x8 b0 = *reinterpret_cast<const bf16x8*>(&Vt[(nt * 16 + l15) * KP + quad * 8]);
            bf16x8 b1 = *reinterpret_cast<const bf16x8*>(&Vt[(nt * 16 + l15) * KP + quad * 8 + 32]);
            oacc[nt] = MFMA_BF16(e0, b0, oacc[nt], 0, 0, 0);
            oacc[nt] = MFMA_BF16(e1, b1, oacc[nt], 0, 0, 0);
        }
    }
    // reduce rowsums over the 16 lanes of each quad
#pragma unroll
    for (int reg = 0; reg < 4; reg++) {
        float s = rsum[reg];
        s += __shfl_xor(s, 1); s += __shfl_xor(s, 2);
        s += __shfl_xor(s, 4); s += __shfl_xor(s, 8);
        rsum[reg] = s;
    }
    const int row0 = w * 16 + quad * 4;
    if (l15 == 0) {
#pragma unroll
        for (int reg = 0; reg < 4; reg++)
            atomicAdd(&rowsum3[bh * 64 + row0 + reg], rsum[reg]);
    }
#pragma unroll
    for (int nt = 0; nt < 4; nt++)
#pragma unroll
        for (int reg = 0; reg < 4; reg++)
            atomicAdd(&W2acc[(bh * 64 + row0 + reg) * 64 + nt * 16 + l15], oacc[nt][reg]);
}

// ---------- E: W = inv(K2) @ (W2acc / rowsum3) via hi/lo MFMA; bf16 hi/lo transposed out ----------
__global__ __launch_bounds__(256) void wmid_kernel(const float* __restrict__ K2invg,
                                                   const float* __restrict__ W2acc,
                                                   const float* __restrict__ rowsum3,
                                                   short* __restrict__ Wth,
                                                   short* __restrict__ Wtl) {
    __shared__ short W2th[4096], W2tl[4096];   // W2^T hi/lo, swizzled
    const int bh = blockIdx.x, t = threadIdx.x;
    const int w = t >> 6, lane = t & 63, quad = lane >> 4, l15 = lane & 15;

    // stage W2^T = (W2acc/rowsum)^T
#pragma unroll
    for (int n16 = 0; n16 < 16; n16++) {
        int f = t + n16 * 256;
        int k = f >> 6, n = f & 63;
        float v = W2acc[bh * 4096 + k * 64 + n] / rowsum3[bh * 64 + k];
        short hi = f2b(v);
        W2th[SWI(n, k)] = hi;
        W2tl[SWI(n, k)] = f2b(v - b2f(hi));
    }
    // A-fragments from K2inv fp32 (global, L2) -> hi/lo regs
    const float* Ar = K2invg + bh * 4096 + (w * 16 + l15) * 64;
    float4 x0 = *reinterpret_cast<const float4*>(Ar + quad * 8);
    float4 x1 = *reinterpret_cast<const float4*>(Ar + quad * 8 + 4);
    float4 x2 = *reinterpret_cast<const float4*>(Ar + quad * 8 + 32);
    float4 x3 = *reinterpret_cast<const float4*>(Ar + quad * 8 + 36);
    bf16x8 ah0, al0, ah1, al1;
    {
        float a[8] = {x0.x, x0.y, x0.z, x0.w, x1.x, x1.y, x1.z, x1.w};
        float b[8] = {x2.x, x2.y, x2.z, x2.w, x3.x, x3.y, x3.z, x3.w};
#pragma unroll
        for (int i = 0; i < 8; i++) {
            short h = f2b(a[i]); ah0[i] = h; al0[i] = f2b(a[i] - b2f(h));
            short g = f2b(b[i]); ah1[i] = g; al1[i] = f2b(b[i] - b2f(g));
        }
    }
    __syncthreads();
#pragma unroll
    for (int nt = 0; nt < 4; nt++) {
        bf16x8 bh0 = *reinterpret_cast<const bf16x8*>(&W2th[SWI(nt * 16 + l15, quad * 8)]);
        bf16x8 bh1 = *reinterpret_cast<const bf16x8*>(&W2th[SWI(nt * 16 + l15, quad * 8 + 32)]);
        bf16x8 bl0 = *reinterpret_cast<const bf16x8*>(&W2tl[SWI(nt * 16 + l15, quad * 8)]);
        bf16x8 bl1 = *reinterpret_cast<const bf16x8*>(&W2tl[SWI(nt * 16 + l15, quad * 8 + 32)]);
        f32x4 cc = {0.f, 0.f, 0.f, 0.f};
        cc = MFMA_BF16(ah0, bh0, cc, 0, 0, 0); cc = MFMA_BF16(ah1, bh1, cc, 0, 0, 0);
        cc = MFMA_BF16(ah0, bl0, cc, 0, 0, 0); cc = MFMA_BF16(ah1, bl1, cc, 0, 0, 0);
        cc = MFMA_BF16(al0, bh0, cc, 0, 0, 0); cc = MFMA_BF16(al1, bh1, cc, 0, 0, 0);
#pragma unroll
        for (int reg = 0; reg < 4; reg++) {
            float wv = cc[reg];
            short hi = f2b(wv);
            int col = nt * 16 + l15, r = w * 16 + quad * 4 + reg;
            Wth[bh * 4096 + col * 64 + r] = hi;              // [dim][lm] transposed
            Wtl[bh * 4096 + col * 64 + r] = f2b(wv - b2f(hi));
        }
    }
}

// ---------- F (MFMA): X = softmax((SCALE*Q) Klm^T) @ W ----------
//            Barrier-free; 4 seq-tiles/block; Klm frags in regs; Q prefetch pipeline.
__global__ __launch_bounds__(256, 4) void final_mfma(const float* __restrict__ Q,
                                                     const short* __restrict__ Klm_b,
                                                     const short* __restrict__ Wth,
                                                     const short* __restrict__ Wtl,
                                                     float* __restrict__ out) {
    __shared__ short Eb[64 * KP];   // A (mm2): [seqrow][landmark] — wave-private rows
    const int sc = blockIdx.x, bh = blockIdx.y, t = threadIdx.x;
    const int w = t >> 6, lane = t & 63, quad = lane >> 4, l15 = lane & 15;
    const int row = w * 16 + l15;

    // Klm fragments into registers once (reused across 4 tiles)
    const bf16x8* Kb = reinterpret_cast<const bf16x8*>(Klm_b + bh * 4096);
    bf16x8 kb[4][2];
#pragma unroll
    for (int nt = 0; nt < 4; nt++) {
        kb[nt][0] = Kb[(nt * 16 + l15) * 8 + quad];
        kb[nt][1] = Kb[(nt * 16 + l15) * 8 + quad + 4];
    }
    const bf16x8* Hb = reinterpret_cast<const bf16x8*>(Wth + bh * 4096);    // [dim][lm]
    const bf16x8* Lb = reinterpret_cast<const bf16x8*>(Wtl + bh * 4096);

    const size_t qbase = ((size_t)bh * 4096 + sc * 256 + row) * 64 + quad * 8;
    // prefetch Q tile 0
    float4 qa = *reinterpret_cast<const float4*>(Q + qbase);
    float4 qb = *reinterpret_cast<const float4*>(Q + qbase + 4);
    float4 qc = *reinterpret_cast<const float4*>(Q + qbase + 32);
    float4 qd = *reinterpret_cast<const float4*>(Q + qbase + 36);

#pragma unroll
    for (int st = 0; st < 4; st++) {
        // build A fragments (scaled, bf16) from current Q regs
        bf16x8 a0, a1;
        a0[0] = f2b(SCALE * qa.x); a0[1] = f2b(SCALE * qa.y);
        a0[2] = f2b(SCALE * qa.z); a0[3] = f2b(SCALE * qa.w);
        a0[4] = f2b(SCALE * qb.x); a0[5] = f2b(SCALE * qb.y);
        a0[6] = f2b(SCALE * qb.z); a0[7] = f2b(SCALE * qb.w);
        a1[0] = f2b(SCALE * qc.x); a1[1] = f2b(SCALE * qc.y);
        a1[2] = f2b(SCALE * qc.z); a1[3] = f2b(SCALE * qc.w);
        a1[4] = f2b(SCALE * qd.x); a1[5] = f2b(SCALE * qd.y);
        a1[6] = f2b(SCALE * qd.z); a1[7] = f2b(SCALE * qd.w);
        // issue next tile's Q loads (fly under this tile's compute)
        if (st < 3) {
            const float* np = Q + qbase + (size_t)(st + 1) * 4096;
            qa = *reinterpret_cast<const float4*>(np);
            qb = *reinterpret_cast<const float4*>(np + 4);
            qc = *reinterpret_cast<const float4*>(np + 32);
            qd = *reinterpret_cast<const float4*>(np + 36);
        }
        // mm1: S = Q . Klm^T ; exp ; rowsum ; Eb
        float rsum[4] = {0.f, 0.f, 0.f, 0.f};
#pragma unroll
        for (int nt = 0; nt < 4; nt++) {
            f32x4 c = {0.f, 0.f, 0.f, 0.f};
            c = MFMA_BF16(a0, kb[nt][0], c, 0, 0, 0);
            c = MFMA_BF16(a1, kb[nt][1], c, 0, 0, 0);
#pragma unroll
            for (int reg = 0; reg < 4; reg++) {
                float e = __expf(c[reg]);
                rsum[reg] += e;
                Eb[(w * 16 + quad * 4 + reg) * KP + nt * 16 + l15] = f2b(e);
            }
        }
#pragma unroll
        for (int reg = 0; reg < 4; reg++) {
            float s = rsum[reg];
            s += __shfl_xor(s, 1); s += __shfl_xor(s, 2);
            s += __shfl_xor(s, 4); s += __shfl_xor(s, 8);
            rsum[reg] = 1.0f / s;
        }
        // mm2: X = Eb . (Wh + Wl)   (wave-private Eb rows -> no barrier)
        bf16x8 e0 = *reinterpret_cast<const bf16x8*>(&Eb[row * KP + quad * 8]);
        bf16x8 e1 = *reinterpret_cast<const bf16x8*>(&Eb[row * KP + quad * 8 + 32]);
        const int row0 = w * 16 + quad * 4;
        const int s0 = sc * 256 + st * 64;
#pragma unroll
        for (int nt = 0; nt < 4; nt++) {
            bf16x8 bh0 = Hb[(nt * 16 + l15) * 8 + quad];
            bf16x8 bh1 = Hb[(nt * 16 + l15) * 8 + quad + 4];
            bf16x8 bl0 = Lb[(nt * 16 + l15) * 8 + quad];
            bf16x8 bl1 = Lb[(nt * 16 + l15) * 8 + quad + 4];
            f32x4 c = {0.f, 0.f, 0.f, 0.f};
            c = MFMA_BF16(e0, bh0, c, 0, 0, 0);
            c = MFMA_BF16(e1, bh1, c, 0, 0, 0);
            c = MFMA_BF16(e0, bl0, c, 0, 0, 0);
            c = MFMA_BF16(e1, bl1, c, 0, 0, 0);
#pragma unroll
            for (int reg = 0; reg < 4; reg++)
                out[((size_t)bh * 4096 + s0 + row0 + reg) * 64 + nt * 16 + l15] =
                    c[reg] * rsum[reg];
        }
    }
}

extern "C" void kernel_launch(void* const* d_in, const int* in_sizes, int n_in,
                              void* d_out, int out_size, void* d_ws, size_t ws_size,
                              hipStream_t stream) {
    const float* Q = (const float*)d_in[0];
    const float* K = (const float*)d_in[1];
    const float* V = (const float*)d_in[2];
    float* out = (float*)d_out;
    float* ws = (float*)d_ws;

    float* K2      = ws;                                   // 262144 fp32
    float* K2inv   = ws + 262144;                          // 262144 fp32
    float* W2acc   = ws + 524288;                          // 262144 fp32, zeroed
    float* rowsum3 = ws + 786432;                          // 4096 fp32, zeroed
    unsigned* colmax = (unsigned*)(ws + 790528);           // 1, zeroed
    short* Qlm_bh  = (short*)(ws + 790532);                // 262144 bf16
    short* Qlm_bl  = Qlm_bh + 262144;
    short* Klm_bh  = Qlm_bl + 262144;
    short* Klm_bl  = Klm_bh + 262144;
    short* Wth     = Klm_bl + 262144;
    short* Wtl     = Wth + 262144;

    hipMemsetAsync(W2acc, 0, (262144 + 4096 + 1) * sizeof(float), stream);

    pool_kernel<<<4096, 256, 0, stream>>>(Q, K, Qlm_bh, Qlm_bl, Klm_bh, Klm_bl);
    k2_kernel<<<64, 256, 0, stream>>>(Qlm_bh, Qlm_bl, Klm_bh, Klm_bl, K2, colmax);
    // blocks 0..63: MFMA Newton-Schulz inverse; blocks 64..2111: k3v
    fused_inv_k3v<<<2112, 256, 0, stream>>>(Qlm_bh, K, V, W2acc, rowsum3, K2, colmax, K2inv);
    wmid_kernel<<<64, 256, 0, stream>>>(K2inv, W2acc, rowsum3, Wth, Wtl);
    final_mfma<<<dim3(16, 64), 256, 0, stream>>>(Q, Klm_bh, Wth, Wtl, out);
}

// Round 7
// 284.649 us; speedup vs baseline: 1.1860x; 1.0522x over previous
//
#include <hip/hip_runtime.h>
#include <hip/hip_bf16.h>

#define KP  72            // bf16 LDS pitch: 144 B row
#define SCALE 0.35355339059327379f

typedef __attribute__((ext_vector_type(8))) short bf16x8;
typedef __attribute__((ext_vector_type(4))) float f32x4;
#define MFMA_BF16 __builtin_amdgcn_mfma_f32_16x16x32_bf16

__device__ __forceinline__ short f2b(float f) {          // fp32 -> bf16 RNE
    unsigned u = __float_as_uint(f);
    u += 0x7fff + ((u >> 16) & 1);
    return (short)(u >> 16);
}
__device__ __forceinline__ float b2f(short h) {
    return __uint_as_float(((unsigned)(unsigned short)h) << 16);
}

// swizzled short-index into a [64][64]-short (pitch 64) LDS tile:
// byte = row*128 + colS*2, XOR'd with (row&7)<<4 -> b128 reads 2-way conflict only
__device__ __forceinline__ int SWI(int row, int colS) {
    return (((row << 7) + (colS << 1)) ^ ((row & 7) << 4)) >> 1;
}

// ---------- A: landmark pooling -> Qlm/Klm hi+lo bf16 (SCALE/64 pre-scaled);
//             also zeroes the W2acc/rowsum3/colmax accumulator block ----------
__global__ __launch_bounds__(256) void pool_kernel(const float* __restrict__ Q,
                                                   const float* __restrict__ K,
                                                   short* __restrict__ Qlm_bh,
                                                   short* __restrict__ Qlm_bl,
                                                   short* __restrict__ Klm_bh,
                                                   short* __restrict__ Klm_bl,
                                                   float* __restrict__ zeroBuf,
                                                   int zeroCount) {
    __shared__ float4 red[256];
    const int blk = blockIdx.x;
    const int t = threadIdx.x;
    const int d4 = t & 15;
    const int rg = t >> 4;
    const float4* Q4 = reinterpret_cast<const float4*>(Q);
    const float4* K4 = reinterpret_cast<const float4*>(K);

    // zero the accumulator workspace (replaces a memset dispatch)
    int zi = blk * 256 + t;
    if (zi < zeroCount) zeroBuf[zi] = 0.f;

    float4 sQ = {0.f, 0.f, 0.f, 0.f}, sK = {0.f, 0.f, 0.f, 0.f};
#pragma unroll
    for (int rr = 0; rr < 4; rr++) {
        int row = blk * 64 + rg * 4 + rr;
        int off4 = (row << 4) + d4;
        float4 q = Q4[off4], k = K4[off4];
        sQ.x += q.x; sQ.y += q.y; sQ.z += q.z; sQ.w += q.w;
        sK.x += k.x; sK.y += k.y; sK.z += k.z; sK.w += k.w;
    }
    const float c = SCALE * (1.0f / 64.0f);
    red[t] = sQ;
    __syncthreads();
    if (t < 16) {
        float4 s = {0.f, 0.f, 0.f, 0.f};
#pragma unroll
        for (int g = 0; g < 16; g++) {
            float4 v = red[g * 16 + t];
            s.x += v.x; s.y += v.y; s.z += v.z; s.w += v.w;
        }
        s.x *= c; s.y *= c; s.z *= c; s.w *= c;
        short h0 = f2b(s.x), h1 = f2b(s.y), h2 = f2b(s.z), h3 = f2b(s.w);
        ushort4 uh = {(unsigned short)h0, (unsigned short)h1,
                      (unsigned short)h2, (unsigned short)h3};
        ushort4 ul = {(unsigned short)f2b(s.x - b2f(h0)), (unsigned short)f2b(s.y - b2f(h1)),
                      (unsigned short)f2b(s.z - b2f(h2)), (unsigned short)f2b(s.w - b2f(h3))};
        *reinterpret_cast<ushort4*>(&Qlm_bh[blk * 64 + t * 4]) = uh;
        *reinterpret_cast<ushort4*>(&Qlm_bl[blk * 64 + t * 4]) = ul;
    }
    __syncthreads();
    red[t] = sK;
    __syncthreads();
    if (t < 16) {
        float4 s = {0.f, 0.f, 0.f, 0.f};
#pragma unroll
        for (int g = 0; g < 16; g++) {
            float4 v = red[g * 16 + t];
            s.x += v.x; s.y += v.y; s.z += v.z; s.w += v.w;
        }
        s.x *= c; s.y *= c; s.z *= c; s.w *= c;
        short h0 = f2b(s.x), h1 = f2b(s.y), h2 = f2b(s.z), h3 = f2b(s.w);
        ushort4 uh = {(unsigned short)h0, (unsigned short)h1,
                      (unsigned short)h2, (unsigned short)h3};
        ushort4 ul = {(unsigned short)f2b(s.x - b2f(h0)), (unsigned short)f2b(s.y - b2f(h1)),
                      (unsigned short)f2b(s.z - b2f(h2)), (unsigned short)f2b(s.w - b2f(h3))};
        *reinterpret_cast<ushort4*>(&Klm_bh[blk * 64 + t * 4]) = uh;
        *reinterpret_cast<ushort4*>(&Klm_bl[blk * 64 + t * 4]) = ul;
    }
}

// ---------- B: K2 = softmax(Qlm Klm^T) via hi/lo MFMA; wave-parallel softmax ----------
__global__ __launch_bounds__(256) void k2_kernel(const short* __restrict__ Qlm_bh,
                                                 const short* __restrict__ Qlm_bl,
                                                 const short* __restrict__ Klm_bh,
                                                 const short* __restrict__ Klm_bl,
                                                 float* __restrict__ K2g,
                                                 unsigned* __restrict__ colmax) {
    __shared__ float csum[16 * 64];
    const int bh = blockIdx.x, t = threadIdx.x;
    const int w = t >> 6, lane = t & 63, quad = lane >> 4, l15 = lane & 15;

    const bf16x8* Ah = reinterpret_cast<const bf16x8*>(Qlm_bh + bh * 4096);
    const bf16x8* Al = reinterpret_cast<const bf16x8*>(Qlm_bl + bh * 4096);
    const bf16x8* Bh = reinterpret_cast<const bf16x8*>(Klm_bh + bh * 4096);
    const bf16x8* Bl = reinterpret_cast<const bf16x8*>(Klm_bl + bh * 4096);
    bf16x8 ah0 = Ah[(w * 16 + l15) * 8 + quad], ah1 = Ah[(w * 16 + l15) * 8 + quad + 4];
    bf16x8 al0 = Al[(w * 16 + l15) * 8 + quad], al1 = Al[(w * 16 + l15) * 8 + quad + 4];

    f32x4 c[4];
#pragma unroll
    for (int nt = 0; nt < 4; nt++) {
        bf16x8 bh0 = Bh[(nt * 16 + l15) * 8 + quad], bh1 = Bh[(nt * 16 + l15) * 8 + quad + 4];
        bf16x8 bl0 = Bl[(nt * 16 + l15) * 8 + quad], bl1 = Bl[(nt * 16 + l15) * 8 + quad + 4];
        f32x4 cc = {0.f, 0.f, 0.f, 0.f};
        cc = MFMA_BF16(ah0, bh0, cc, 0, 0, 0); cc = MFMA_BF16(ah1, bh1, cc, 0, 0, 0);
        cc = MFMA_BF16(ah0, bl0, cc, 0, 0, 0); cc = MFMA_BF16(ah1, bl1, cc, 0, 0, 0);
        cc = MFMA_BF16(al0, bh0, cc, 0, 0, 0); cc = MFMA_BF16(al1, bh1, cc, 0, 0, 0);
        c[nt] = cc;
    }
    float m[4] = {-1e30f, -1e30f, -1e30f, -1e30f};
#pragma unroll
    for (int nt = 0; nt < 4; nt++)
#pragma unroll
        for (int reg = 0; reg < 4; reg++) m[reg] = fmaxf(m[reg], c[nt][reg]);
#pragma unroll
    for (int reg = 0; reg < 4; reg++) {
        float v = m[reg];
        v = fmaxf(v, __shfl_xor(v, 1)); v = fmaxf(v, __shfl_xor(v, 2));
        v = fmaxf(v, __shfl_xor(v, 4)); v = fmaxf(v, __shfl_xor(v, 8));
        m[reg] = v;
    }
    float e[4][4];
    float rs[4] = {0.f, 0.f, 0.f, 0.f};
#pragma unroll
    for (int nt = 0; nt < 4; nt++)
#pragma unroll
        for (int reg = 0; reg < 4; reg++) {
            float ev = __expf(c[nt][reg] - m[reg]);
            e[nt][reg] = ev; rs[reg] += ev;
        }
#pragma unroll
    for (int reg = 0; reg < 4; reg++) {
        float v = rs[reg];
        v += __shfl_xor(v, 1); v += __shfl_xor(v, 2);
        v += __shfl_xor(v, 4); v += __shfl_xor(v, 8);
        rs[reg] = 1.0f / v;
    }
    float ps[4] = {0.f, 0.f, 0.f, 0.f};
#pragma unroll
    for (int nt = 0; nt < 4; nt++) {
#pragma unroll
        for (int reg = 0; reg < 4; reg++) {
            float p = e[nt][reg] * rs[reg];
            K2g[bh * 4096 + (w * 16 + quad * 4 + reg) * 64 + nt * 16 + l15] = p;
            ps[nt] += p;
        }
        csum[(w * 4 + quad) * 64 + nt * 16 + l15] = ps[nt];
    }
    __syncthreads();
    if (t < 64) {
        float s = 0.f;
#pragma unroll
        for (int i = 0; i < 16; i++) s += csum[i * 64 + t];
        atomicMax(colmax, __float_as_uint(s));
    }
}

// ---------- C+D fused: blocks 0..63 Newton-Schulz inverse (MFMA hi/lo, 48 KB LDS,
//            K2 LHS-fragments in registers); blocks 64..1087 k3v (16 chunks x 4 tiles,
//            halved atomic traffic, 3 blocks/CU). ----------
__global__ __launch_bounds__(256) void fused_inv_k3v(const short* __restrict__ Qlm_bh,
                                                     const float* __restrict__ K,
                                                     const float* __restrict__ V,
                                                     float* __restrict__ W2acc,
                                                     float* __restrict__ rowsum3,
                                                     const float* __restrict__ K2g,
                                                     const unsigned* __restrict__ colmax,
                                                     float* __restrict__ K2invg) {
    // inverse: 6 x [64][64]-short swizzled tiles = 48 KB; k3v: 3 x 64*KP = 27.6 KB
    __shared__ __align__(16) char smem[49152];
    const int t = threadIdx.x;
    const int w = t >> 6, lane = t & 63, quad = lane >> 4, l15 = lane & 15;

    if (blockIdx.x < 64) {
        // ===== Newton-Schulz inverse, MFMA bf16 hi/lo (4-term, ~2^-17 rel) ======
        short* Ath = reinterpret_cast<short*>(smem);       // A^T hi
        short* Atl = Ath + 4096;                           // A^T lo
        short* B1h = Atl + 4096;                           // V^T / P / V'^T
        short* B1l = B1h + 4096;
        short* B2h = B1l + 4096;                           // V / Q2 / V'
        short* B2l = B2h + 4096;
        const int bh = blockIdx.x;
        const float scv = 1.0f / __uint_as_float(*colmax);
        const float* Kg = K2g + bh * 4096;

        // K2 LHS fragments (M1), constant across iterations -> registers
        bf16x8 kh0, kl0, kh1, kl1;
        {
            const float* Kr = Kg + (w * 16 + l15) * 64;
            float4 x0 = *reinterpret_cast<const float4*>(Kr + quad * 8);
            float4 x1 = *reinterpret_cast<const float4*>(Kr + quad * 8 + 4);
            float4 x2 = *reinterpret_cast<const float4*>(Kr + quad * 8 + 32);
            float4 x3 = *reinterpret_cast<const float4*>(Kr + quad * 8 + 36);
            float a[8] = {x0.x, x0.y, x0.z, x0.w, x1.x, x1.y, x1.z, x1.w};
            float b[8] = {x2.x, x2.y, x2.z, x2.w, x3.x, x3.y, x3.z, x3.w};
#pragma unroll
            for (int i = 0; i < 8; i++) {
                short h = f2b(a[i]); kh0[i] = h; kl0[i] = f2b(a[i] - b2f(h));
                short g = f2b(b[i]); kh1[i] = g; kl1[i] = f2b(b[i] - b2f(g));
            }
        }
        // ---- stage B1 = scv*K2 (= V0^T), B2 = scv*K2^T (= V0), hi/lo swizzled ----
#pragma unroll
        for (int n = 0; n < 4; n++) {
            int f4 = t + n * 256;
            int r = f4 >> 4, c0 = (f4 & 15) * 4;
            float4 kk = *reinterpret_cast<const float4*>(Kg + r * 64 + c0);
            float s0 = scv * kk.x, s1 = scv * kk.y, s2 = scv * kk.z, s3 = scv * kk.w;
            short g0 = f2b(s0), g1 = f2b(s1), g2 = f2b(s2), g3 = f2b(s3);
            ushort4 vh = {(unsigned short)g0, (unsigned short)g1,
                          (unsigned short)g2, (unsigned short)g3};
            ushort4 vl = {(unsigned short)f2b(s0 - b2f(g0)), (unsigned short)f2b(s1 - b2f(g1)),
                          (unsigned short)f2b(s2 - b2f(g2)), (unsigned short)f2b(s3 - b2f(g3))};
            *reinterpret_cast<ushort4*>(&B1h[SWI(r, c0)]) = vh;
            *reinterpret_cast<ushort4*>(&B1l[SWI(r, c0)]) = vl;
            float t0 = scv * Kg[(c0 + 0) * 64 + r];
            float t1 = scv * Kg[(c0 + 1) * 64 + r];
            float t2 = scv * Kg[(c0 + 2) * 64 + r];
            float t3 = scv * Kg[(c0 + 3) * 64 + r];
            short e0 = f2b(t0), e1 = f2b(t1), e2 = f2b(t2), e3 = f2b(t3);
            ushort4 th = {(unsigned short)e0, (unsigned short)e1,
                          (unsigned short)e2, (unsigned short)e3};
            ushort4 tl = {(unsigned short)f2b(t0 - b2f(e0)), (unsigned short)f2b(t1 - b2f(e1)),
                          (unsigned short)f2b(t2 - b2f(e2)), (unsigned short)f2b(t3 - b2f(e3))};
            *reinterpret_cast<ushort4*>(&B2h[SWI(r, c0)]) = th;
            *reinterpret_cast<ushort4*>(&B2l[SWI(r, c0)]) = tl;
        }
        // V in fp32 registers: vreg[nt][reg] = V0[w*16+quad*4+reg][nt*16+l15]
        float vreg[4][4];
#pragma unroll
        for (int nt = 0; nt < 4; nt++) {
            float4 vv = *reinterpret_cast<const float4*>(
                Kg + (nt * 16 + l15) * 64 + w * 16 + quad * 4);
            vreg[nt][0] = scv * vv.x; vreg[nt][1] = scv * vv.y;
            vreg[nt][2] = scv * vv.z; vreg[nt][3] = scv * vv.w;
        }
        __syncthreads();

#define LOADA(Lh, Ll) \
        bf16x8 ah0 = *reinterpret_cast<const bf16x8*>(&Lh[SWI(w * 16 + l15, quad * 8)]); \
        bf16x8 ah1 = *reinterpret_cast<const bf16x8*>(&Lh[SWI(w * 16 + l15, quad * 8 + 32)]); \
        bf16x8 al0 = *reinterpret_cast<const bf16x8*>(&Ll[SWI(w * 16 + l15, quad * 8)]); \
        bf16x8 al1 = *reinterpret_cast<const bf16x8*>(&Ll[SWI(w * 16 + l15, quad * 8 + 32)]);
#define PROD8(AH0, AH1, AL0, AL1, Bh, Bl, nt, c) { \
        bf16x8 bh0 = *reinterpret_cast<const bf16x8*>(&Bh[SWI(nt * 16 + l15, quad * 8)]); \
        bf16x8 bh1 = *reinterpret_cast<const bf16x8*>(&Bh[SWI(nt * 16 + l15, quad * 8 + 32)]); \
        bf16x8 bl0 = *reinterpret_cast<const bf16x8*>(&Bl[SWI(nt * 16 + l15, quad * 8)]); \
        bf16x8 bl1 = *reinterpret_cast<const bf16x8*>(&Bl[SWI(nt * 16 + l15, quad * 8 + 32)]); \
        c = MFMA_BF16(AH0, bh0, c, 0, 0, 0); c = MFMA_BF16(AH1, bh1, c, 0, 0, 0); \
        c = MFMA_BF16(AH0, bl0, c, 0, 0, 0); c = MFMA_BF16(AH1, bl1, c, 0, 0, 0); \
        c = MFMA_BF16(AL0, bh0, c, 0, 0, 0); c = MFMA_BF16(AL1, bh1, c, 0, 0, 0); \
        c = MFMA_BF16(AL0, bl0, c, 0, 0, 0); c = MFMA_BF16(AL1, bl1, c, 0, 0, 0); }

        for (int iter = 0; iter < 6; iter++) {
            // M1: A = K·V  (LHS = reg K-frags, B = B1 = V^T) -> write A^T hi/lo
#pragma unroll
            for (int nt = 0; nt < 4; nt++) {
                f32x4 c = {0.f, 0.f, 0.f, 0.f};
                PROD8(kh0, kh1, kl0, kl1, B1h, B1l, nt, c)
                short h0 = f2b(c[0]), h1 = f2b(c[1]), h2 = f2b(c[2]), h3 = f2b(c[3]);
                ushort4 uh = {(unsigned short)h0, (unsigned short)h1,
                              (unsigned short)h2, (unsigned short)h3};
                ushort4 ul = {(unsigned short)f2b(c[0] - b2f(h0)),
                              (unsigned short)f2b(c[1] - b2f(h1)),
                              (unsigned short)f2b(c[2] - b2f(h2)),
                              (unsigned short)f2b(c[3] - b2f(h3))};
                *reinterpret_cast<ushort4*>(&Ath[SWI(nt * 16 + l15, w * 16 + quad * 4)]) = uh;
                *reinterpret_cast<ushort4*>(&Atl[SWI(nt * 16 + l15, w * 16 + quad * 4)]) = ul;
            }
            __syncthreads();   // Ath publish + B1 reads (M1) complete
            // M2: P = V·A (LHS = B2 own rows) -> p regs + P rows into B1 (own rows)
            float p[4][4];
            {
                LOADA(B2h, B2l)
#pragma unroll
                for (int nt = 0; nt < 4; nt++) {
                    f32x4 c = {0.f, 0.f, 0.f, 0.f};
                    PROD8(ah0, ah1, al0, al1, Ath, Atl, nt, c)
#pragma unroll
                    for (int reg = 0; reg < 4; reg++) {
                        p[nt][reg] = c[reg];
                        short hh = f2b(c[reg]);
                        B1h[SWI(w * 16 + quad * 4 + reg, nt * 16 + l15)] = hh;
                        B1l[SWI(w * 16 + quad * 4 + reg, nt * 16 + l15)] = f2b(c[reg] - b2f(hh));
                    }
                }
            }
            // M3: Q2 = P·A (LHS = B1 own rows, same-wave) -> q regs + Q2 rows into B2
            float q[4][4];
            {
                LOADA(B1h, B1l)
#pragma unroll
                for (int nt = 0; nt < 4; nt++) {
                    f32x4 c = {0.f, 0.f, 0.f, 0.f};
                    PROD8(ah0, ah1, al0, al1, Ath, Atl, nt, c)
#pragma unroll
                    for (int reg = 0; reg < 4; reg++) {
                        q[nt][reg] = c[reg];
                        short hh = f2b(c[reg]);
                        B2h[SWI(w * 16 + quad * 4 + reg, nt * 16 + l15)] = hh;
                        B2l[SWI(w * 16 + quad * 4 + reg, nt * 16 + l15)] = f2b(c[reg] - b2f(hh));
                    }
                }
            }
            // M4: R = Q2·A (LHS = B2 own rows, same-wave); combo in fp32 regs
            {
                LOADA(B2h, B2l)
#pragma unroll
                for (int nt = 0; nt < 4; nt++) {
                    f32x4 c = {0.f, 0.f, 0.f, 0.f};
                    PROD8(ah0, ah1, al0, al1, Ath, Atl, nt, c)
#pragma unroll
                    for (int reg = 0; reg < 4; reg++)
                        vreg[nt][reg] = 0.25f * (13.f * vreg[nt][reg] - 15.f * p[nt][reg]
                                                 + 7.f * q[nt][reg] - c[reg]);
                }
            }
            __syncthreads();   // all waves done reading B1 (M3) / Ath (M4)
            // publish V': rows into B2 (own) and V'^T into B1 (cross-wave cols)
#pragma unroll
            for (int nt = 0; nt < 4; nt++) {
                short h0 = f2b(vreg[nt][0]), h1 = f2b(vreg[nt][1]);
                short h2 = f2b(vreg[nt][2]), h3 = f2b(vreg[nt][3]);
                short g0 = f2b(vreg[nt][0] - b2f(h0)), g1 = f2b(vreg[nt][1] - b2f(h1));
                short g2 = f2b(vreg[nt][2] - b2f(h2)), g3 = f2b(vreg[nt][3] - b2f(h3));
                ushort4 uh = {(unsigned short)h0, (unsigned short)h1,
                              (unsigned short)h2, (unsigned short)h3};
                ushort4 ul = {(unsigned short)g0, (unsigned short)g1,
                              (unsigned short)g2, (unsigned short)g3};
                *reinterpret_cast<ushort4*>(&B1h[SWI(nt * 16 + l15, w * 16 + quad * 4)]) = uh;
                *reinterpret_cast<ushort4*>(&B1l[SWI(nt * 16 + l15, w * 16 + quad * 4)]) = ul;
                B2h[SWI(w * 16 + quad * 4 + 0, nt * 16 + l15)] = h0;
                B2h[SWI(w * 16 + quad * 4 + 1, nt * 16 + l15)] = h1;
                B2h[SWI(w * 16 + quad * 4 + 2, nt * 16 + l15)] = h2;
                B2h[SWI(w * 16 + quad * 4 + 3, nt * 16 + l15)] = h3;
                B2l[SWI(w * 16 + quad * 4 + 0, nt * 16 + l15)] = g0;
                B2l[SWI(w * 16 + quad * 4 + 1, nt * 16 + l15)] = g1;
                B2l[SWI(w * 16 + quad * 4 + 2, nt * 16 + l15)] = g2;
                B2l[SWI(w * 16 + quad * 4 + 3, nt * 16 + l15)] = g3;
            }
            __syncthreads();   // V' visible before next M1 reads B1
        }
#undef LOADA
#undef PROD8
#pragma unroll
        for (int nt = 0; nt < 4; nt++)
#pragma unroll
            for (int reg = 0; reg < 4; reg++)
                K2invg[bh * 4096 + (w * 16 + quad * 4 + reg) * 64 + nt * 16 + l15] =
                    vreg[nt][reg];
        return;
    }

    // ================= k3v: W2acc += exp(Qlm (SCALE*K)^T) @ V =================
    short* Kt = reinterpret_cast<short*>(smem);            // B (mm1): [key][dim]
    short* Vt = Kt + 64 * KP;                              // B (mm2): [dim][key]
    short* Eb = Vt + 64 * KP;                              // A (mm2): [landmark][key]
    const int idx = blockIdx.x - 64;
    const int chunk = idx & 15, bh = idx >> 4;             // 16 chunks x 64 bh
    const float4* K4 = reinterpret_cast<const float4*>(K);
    const float4* V4 = reinterpret_cast<const float4*>(V);
    const int dg = t & 15;          // dim-group 0..15 (float4 index)
    const int kr = t >> 4;          // K staging: key row base; V staging: key-group
    const int bhBase = bh * 4096;

    // A fragments straight from Qlm_bh (bf16, L2-resident)
    const bf16x8* Qb = reinterpret_cast<const bf16x8*>(Qlm_bh + bh * 4096);
    bf16x8 a0 = Qb[(w * 16 + l15) * 8 + quad];
    bf16x8 a1 = Qb[(w * 16 + l15) * 8 + quad + 4];

    f32x4 oacc[4];
    float rsum[4];
#pragma unroll
    for (int nt = 0; nt < 4; nt++) { oacc[nt] = (f32x4){0.f, 0.f, 0.f, 0.f}; rsum[nt] = 0.f; }

    const int sb0 = chunk * 256;
    for (int tile = 0; tile < 4; tile++) {
        const int sb = sb0 + tile * 64;
        __syncthreads();   // prev tile's MFMA done reading Kt/Vt
        // ---- stage K (scaled, row-major): rows kr+16n at dim-group dg ----
#pragma unroll
        for (int n = 0; n < 4; n++) {
            float4 kk = K4[(bhBase + sb + kr + 16 * n) * 16 + dg];
            ushort4 uk = { (unsigned short)f2b(SCALE * kk.x), (unsigned short)f2b(SCALE * kk.y),
                           (unsigned short)f2b(SCALE * kk.z), (unsigned short)f2b(SCALE * kk.w) };
            *reinterpret_cast<ushort4*>(&Kt[(kr + 16 * n) * KP + dg * 4]) = uk;
        }
        // ---- stage V^T: thread owns keys kr*4..+3 at dims dg*4..+3 ----
        {
            float4 pv0 = V4[(bhBase + sb + kr * 4 + 0) * 16 + dg];
            float4 pv1 = V4[(bhBase + sb + kr * 4 + 1) * 16 + dg];
            float4 pv2 = V4[(bhBase + sb + kr * 4 + 2) * 16 + dg];
            float4 pv3 = V4[(bhBase + sb + kr * 4 + 3) * 16 + dg];
            ushort4 u0 = { (unsigned short)f2b(pv0.x), (unsigned short)f2b(pv1.x),
                           (unsigned short)f2b(pv2.x), (unsigned short)f2b(pv3.x) };
            ushort4 u1 = { (unsigned short)f2b(pv0.y), (unsigned short)f2b(pv1.y),
                           (unsigned short)f2b(pv2.y), (unsigned short)f2b(pv3.y) };
            ushort4 u2 = { (unsigned short)f2b(pv0.z), (unsigned short)f2b(pv1.z),
                           (unsigned short)f2b(pv2.z), (unsigned short)f2b(pv3.z) };
            ushort4 u3 = { (unsigned short)f2b(pv0.w), (unsigned short)f2b(pv1.w),
                           (unsigned short)f2b(pv2.w), (unsigned short)f2b(pv3.w) };
            *reinterpret_cast<ushort4*>(&Vt[(dg * 4 + 0) * KP + kr * 4]) = u0;
            *reinterpret_cast<ushort4*>(&Vt[(dg * 4 + 1) * KP + kr * 4]) = u1;
            *reinterpret_cast<ushort4*>(&Vt[(dg * 4 + 2) * KP + kr * 4]) = u2;
            *reinterpret_cast<ushort4*>(&Vt[(dg * 4 + 3) * KP + kr * 4]) = u3;
        }
        __syncthreads();
        // matmul1: S[m=16w.., n=key] = Qlm . Kt^T
#pragma unroll
        for (int nt = 0; nt < 4; nt++) {
            bf16x8 b0 = *reinterpret_cast<const bf16x8*>(&Kt[(nt * 16 + l15) * KP + quad * 8]);
            bf16x8 b1 = *reinterpret_cast<const bf16x8*>(&Kt[(nt * 16 + l15) * KP + quad * 8 + 32]);
            f32x4 c = {0.f, 0.f, 0.f, 0.f};
            c = MFMA_BF16(a0, b0, c, 0, 0, 0);
            c = MFMA_BF16(a1, b1, c, 0, 0, 0);
#pragma unroll
            for (int reg = 0; reg < 4; reg++) {
                float e = __expf(c[reg]);
                rsum[reg] += e;
                Eb[(w * 16 + quad * 4 + reg) * KP + nt * 16 + l15] = f2b(e);
            }
        }
        // matmul2: oacc += E . Vt^T   (wave reads only its own E rows -> no barrier)
        bf16x8 e0 = *reinterpret_cast<const bf16x8*>(&Eb[(w * 16 + l15) * KP + quad * 8]);
        bf16x8 e1 = *reinterpret_cast<const bf16x8*>(&Eb[(w * 16 + l15) * KP + quad * 8 + 32]);
#pragma unroll
        for (int nt = 0; nt < 4; nt++) {
            bf16x8 b0 = *reinterpret_cast<const bf16x8*>(&Vt[(nt * 16 + l15) * KP + quad * 8]);
            bf16x8 b1 = *reinterpret_cast<const bf16x8*>(&Vt[(nt * 16 + l15) * KP + quad * 8 + 32]);
            oacc[nt] = MFMA_BF16(e0, b0, oacc[nt], 0, 0, 0);
            oacc[nt] = MFMA_BF16(e1, b1, oacc[nt], 0, 0, 0);
        }
    }
    // reduce rowsums over the 16 lanes of each quad
#pragma unroll
    for (int reg = 0; reg < 4; reg++) {
        float s = rsum[reg];
        s += __shfl_xor(s, 1); s += __shfl_xor(s, 2);
        s += __shfl_xor(s, 4); s += __shfl_xor(s, 8);
        rsum[reg] = s;
    }
    const int row0 = w * 16 + quad * 4;
    if (l15 == 0) {
#pragma unroll
        for (int reg = 0; reg < 4; reg++)
            atomicAdd(&rowsum3[bh * 64 + row0 + reg], rsum[reg]);
    }
#pragma unroll
    for (int nt = 0; nt < 4; nt++)
#pragma unroll
        for (int reg = 0; reg < 4; reg++)
            atomicAdd(&W2acc[(bh * 64 + row0 + reg) * 64 + nt * 16 + l15], oacc[nt][reg]);
}

// ---------- E: W = inv(K2) @ (W2acc / rowsum3) via hi/lo MFMA; bf16 hi/lo transposed out ----------
__global__ __launch_bounds__(256) void wmid_kernel(const float* __restrict__ K2invg,
                                                   const float* __restrict__ W2acc,
                                                   const float* __restrict__ rowsum3,
                                                   short* __restrict__ Wth,
                                                   short* __restrict__ Wtl) {
    __shared__ short W2th[4096], W2tl[4096];   // W2^T hi/lo, swizzled
    const int bh = blockIdx.x, t = threadIdx.x;
    const int w = t >> 6, lane = t & 63, quad = lane >> 4, l15 = lane & 15;

#pragma unroll
    for (int n16 = 0; n16 < 16; n16++) {
        int f = t + n16 * 256;
        int k = f >> 6, n = f & 63;
        float v = W2acc[bh * 4096 + k * 64 + n] / rowsum3[bh * 64 + k];
        short hi = f2b(v);
        W2th[SWI(n, k)] = hi;
        W2tl[SWI(n, k)] = f2b(v - b2f(hi));
    }
    const float* Ar = K2invg + bh * 4096 + (w * 16 + l15) * 64;
    float4 x0 = *reinterpret_cast<const float4*>(Ar + quad * 8);
    float4 x1 = *reinterpret_cast<const float4*>(Ar + quad * 8 + 4);
    float4 x2 = *reinterpret_cast<const float4*>(Ar + quad * 8 + 32);
    float4 x3 = *reinterpret_cast<const float4*>(Ar + quad * 8 + 36);
    bf16x8 ah0, al0, ah1, al1;
    {
        float a[8] = {x0.x, x0.y, x0.z, x0.w, x1.x, x1.y, x1.z, x1.w};
        float b[8] = {x2.x, x2.y, x2.z, x2.w, x3.x, x3.y, x3.z, x3.w};
#pragma unroll
        for (int i = 0; i < 8; i++) {
            short h = f2b(a[i]); ah0[i] = h; al0[i] = f2b(a[i] - b2f(h));
            short g = f2b(b[i]); ah1[i] = g; al1[i] = f2b(b[i] - b2f(g));
        }
    }
    __syncthreads();
#pragma unroll
    for (int nt = 0; nt < 4; nt++) {
        bf16x8 bh0 = *reinterpret_cast<const bf16x8*>(&W2th[SWI(nt * 16 + l15, quad * 8)]);
        bf16x8 bh1 = *reinterpret_cast<const bf16x8*>(&W2th[SWI(nt * 16 + l15, quad * 8 + 32)]);
        bf16x8 bl0 = *reinterpret_cast<const bf16x8*>(&W2tl[SWI(nt * 16 + l15, quad * 8)]);
        bf16x8 bl1 = *reinterpret_cast<const bf16x8*>(&W2tl[SWI(nt * 16 + l15, quad * 8 + 32)]);
        f32x4 cc = {0.f, 0.f, 0.f, 0.f};
        cc = MFMA_BF16(ah0, bh0, cc, 0, 0, 0); cc = MFMA_BF16(ah1, bh1, cc, 0, 0, 0);
        cc = MFMA_BF16(ah0, bl0, cc, 0, 0, 0); cc = MFMA_BF16(ah1, bl1, cc, 0, 0, 0);
        cc = MFMA_BF16(al0, bh0, cc, 0, 0, 0); cc = MFMA_BF16(al1, bh1, cc, 0, 0, 0);
#pragma unroll
        for (int reg = 0; reg < 4; reg++) {
            float wv = cc[reg];
            short hi = f2b(wv);
            int col = nt * 16 + l15, r = w * 16 + quad * 4 + reg;
            Wth[bh * 4096 + col * 64 + r] = hi;              // [dim][lm] transposed
            Wtl[bh * 4096 + col * 64 + r] = f2b(wv - b2f(hi));
        }
    }
}

// ---------- F (MFMA): X = softmax((SCALE*Q) Klm^T) @ W ----------
//            Barrier-free; 4 seq-tiles/block; 2-deep Q register prefetch.
__global__ __launch_bounds__(256, 4) void final_mfma(const float* __restrict__ Q,
                                                     const short* __restrict__ Klm_b,
                                                     const short* __restrict__ Wth,
                                                     const short* __restrict__ Wtl,
                                                     float* __restrict__ out) {
    __shared__ short Eb[64 * KP];   // A (mm2): [seqrow][landmark] — wave-private rows
    const int sc = blockIdx.x, bh = blockIdx.y, t = threadIdx.x;
    const int w = t >> 6, lane = t & 63, quad = lane >> 4, l15 = lane & 15;
    const int row = w * 16 + l15;

    // Klm fragments into registers once (reused across 4 tiles)
    const bf16x8* Kb = reinterpret_cast<const bf16x8*>(Klm_b + bh * 4096);
    bf16x8 kb[4][2];
#pragma unroll
    for (int nt = 0; nt < 4; nt++) {
        kb[nt][0] = Kb[(nt * 16 + l15) * 8 + quad];
        kb[nt][1] = Kb[(nt * 16 + l15) * 8 + quad + 4];
    }
    const bf16x8* Hb = reinterpret_cast<const bf16x8*>(Wth + bh * 4096);    // [dim][lm]
    const bf16x8* Lb = reinterpret_cast<const bf16x8*>(Wtl + bh * 4096);

    const size_t qbase = ((size_t)bh * 4096 + sc * 256 + row) * 64 + quad * 8;

#define FM_LOADQ(p0, p1, p2, p3, stt) { \
        const float* np = Q + qbase + (size_t)(stt) * 4096; \
        p0 = *reinterpret_cast<const float4*>(np); \
        p1 = *reinterpret_cast<const float4*>(np + 4); \
        p2 = *reinterpret_cast<const float4*>(np + 32); \
        p3 = *reinterpret_cast<const float4*>(np + 36); }

#define FM_TILE(p0, p1, p2, p3, stt) { \
        bf16x8 a0, a1; \
        a0[0] = f2b(SCALE * p0.x); a0[1] = f2b(SCALE * p0.y); \
        a0[2] = f2b(SCALE * p0.z); a0[3] = f2b(SCALE * p0.w); \
        a0[4] = f2b(SCALE * p1.x); a0[5] = f2b(SCALE * p1.y); \
        a0[6] = f2b(SCALE * p1.z); a0[7] = f2b(SCALE * p1.w); \
        a1[0] = f2b(SCALE * p2.x); a1[1] = f2b(SCALE * p2.y); \
        a1[2] = f2b(SCALE * p2.z); a1[3] = f2b(SCALE * p2.w); \
        a1[4] = f2b(SCALE * p3.x); a1[5] = f2b(SCALE * p3.y); \
        a1[6] = f2b(SCALE * p3.z); a1[7] = f2b(SCALE * p3.w); \
        float rsum[4] = {0.f, 0.f, 0.f, 0.f}; \
        _Pragma("unroll") \
        for (int nt = 0; nt < 4; nt++) { \
            f32x4 c = {0.f, 0.f, 0.f, 0.f}; \
            c = MFMA_BF16(a0, kb[nt][0], c, 0, 0, 0); \
            c = MFMA_BF16(a1, kb[nt][1], c, 0, 0, 0); \
            _Pragma("unroll") \
            for (int reg = 0; reg < 4; reg++) { \
                float e = __expf(c[reg]); \
                rsum[reg] += e; \
                Eb[(w * 16 + quad * 4 + reg) * KP + nt * 16 + l15] = f2b(e); \
            } \
        } \
        _Pragma("unroll") \
        for (int reg = 0; reg < 4; reg++) { \
            float s = rsum[reg]; \
            s += __shfl_xor(s, 1); s += __shfl_xor(s, 2); \
            s += __shfl_xor(s, 4); s += __shfl_xor(s, 8); \
            rsum[reg] = 1.0f / s; \
        } \
        bf16x8 e0 = *reinterpret_cast<const bf16x8*>(&Eb[row * KP + quad * 8]); \
        bf16x8 e1 = *reinterpret_cast<const bf16x8*>(&Eb[row * KP + quad * 8 + 32]); \
        const int row0 = w * 16 + quad * 4; \
        const int s0 = sc * 256 + (stt) * 64; \
        _Pragma("unroll") \
        for (int nt = 0; nt < 4; nt++) { \
            bf16x8 bh0 = Hb[(nt * 16 + l15) * 8 + quad]; \
            bf16x8 bh1 = Hb[(nt * 16 + l15) * 8 + quad + 4]; \
            bf16x8 bl0 = Lb[(nt * 16 + l15) * 8 + quad]; \
            bf16x8 bl1 = Lb[(nt * 16 + l15) * 8 + quad + 4]; \
            f32x4 c = {0.f, 0.f, 0.f, 0.f}; \
            c = MFMA_BF16(e0, bh0, c, 0, 0, 0); \
            c = MFMA_BF16(e1, bh1, c, 0, 0, 0); \
            c = MFMA_BF16(e0, bl0, c, 0, 0, 0); \
            c = MFMA_BF16(e1, bl1, c, 0, 0, 0); \
            _Pragma("unroll") \
            for (int reg = 0; reg < 4; reg++) \
                out[((size_t)bh * 4096 + s0 + row0 + reg) * 64 + nt * 16 + l15] = \
                    c[reg] * rsum[reg]; \
        } }

    // 2-deep register double-buffer: tiles 0,1 in flight; consume/refill.
    float4 qa0, qa1, qa2, qa3, qb0, qb1, qb2, qb3;
    FM_LOADQ(qa0, qa1, qa2, qa3, 0)
    FM_LOADQ(qb0, qb1, qb2, qb3, 1)
    FM_TILE(qa0, qa1, qa2, qa3, 0)
    FM_LOADQ(qa0, qa1, qa2, qa3, 2)
    FM_TILE(qb0, qb1, qb2, qb3, 1)
    FM_LOADQ(qb0, qb1, qb2, qb3, 3)
    FM_TILE(qa0, qa1, qa2, qa3, 2)
    FM_TILE(qb0, qb1, qb2, qb3, 3)
#undef FM_LOADQ
#undef FM_TILE
}

extern "C" void kernel_launch(void* const* d_in, const int* in_sizes, int n_in,
                              void* d_out, int out_size, void* d_ws, size_t ws_size,
                              hipStream_t stream) {
    const float* Q = (const float*)d_in[0];
    const float* K = (const float*)d_in[1];
    const float* V = (const float*)d_in[2];
    float* out = (float*)d_out;
    float* ws = (float*)d_ws;

    float* K2      = ws;                                   // 262144 fp32
    float* K2inv   = ws + 262144;                          // 262144 fp32
    float* W2acc   = ws + 524288;                          // 262144 fp32, zeroed by pool
    float* rowsum3 = ws + 786432;                          // 4096 fp32, zeroed by pool
    unsigned* colmax = (unsigned*)(ws + 790528);           // 1, zeroed by pool
    short* Qlm_bh  = (short*)(ws + 790532);                // 262144 bf16
    short* Qlm_bl  = Qlm_bh + 262144;
    short* Klm_bh  = Qlm_bl + 262144;
    short* Klm_bl  = Klm_bh + 262144;
    short* Wth     = Klm_bl + 262144;
    short* Wtl     = Wth + 262144;

    pool_kernel<<<4096, 256, 0, stream>>>(Q, K, Qlm_bh, Qlm_bl, Klm_bh, Klm_bl,
                                          W2acc, 262144 + 4096 + 1);
    k2_kernel<<<64, 256, 0, stream>>>(Qlm_bh, Qlm_bl, Klm_bh, Klm_bl, K2, colmax);
    // blocks 0..63: MFMA Newton-Schulz inverse; blocks 64..1087: k3v (16 chunks x 64 bh)
    fused_inv_k3v<<<1088, 256, 0, stream>>>(Qlm_bh, K, V, W2acc, rowsum3, K2, colmax, K2inv);
    wmid_kernel<<<64, 256, 0, stream>>>(K2inv, W2acc, rowsum3, Wth, Wtl);
    final_mfma<<<dim3(16, 64), 256, 0, stream>>>(Q, Klm_bh, Wth, Wtl, out);
}